// Round 4
// baseline (2267.747 us; speedup 1.0000x reference)
//
#include <hip/hip_runtime.h>
#include <hip/hip_fp16.h>
#include <math.h>

#define NN 50000
#define EE 800000
#define HIDDEN 128
#define NGRAPH 50
#define GEMM_TILES ((NN + 63) / 64)

typedef _Float16 half8 __attribute__((ext_vector_type(8)));
typedef float f32x4 __attribute__((ext_vector_type(4)));

// ---------------- CSR degree count + weight transpose (union grid) ----------------
__global__ void k_degprep(const int* __restrict__ eidx, int* __restrict__ cnt,
                          const float* __restrict__ Wq, const float* __restrict__ Wk,
                          const float* __restrict__ Wv, const float* __restrict__ Ws,
                          _Float16* __restrict__ wt) {
    int b = blockIdx.x;
    int t = threadIdx.x;
    if (b < 3125) {
        int e = b * 256 + t;
        if (e < EE) atomicAdd(&cnt[eidx[EE + e]], 1);
    } else {
        int idx = (b - 3125) * 256 + t;   // 12 * 16384 fp16 transposed weights
        if (idx < 12 * 16384) {
            int mat = idx >> 14;
            int l = mat >> 2, w = mat & 3;
            int nk = idx & 16383;
            int n = nk >> 7, k = nk & 127;
            const float* W = (w == 0 ? Wq : w == 1 ? Wk : w == 2 ? Wv : Ws) + (size_t)l * 16384;
            wt[idx] = (_Float16)W[k * 128 + n];
        }
    }
}

// scan + housekeeping: exclusive-scan deg->row_ptr (4 elems/thread), zero cnt,
// zero bn_acc3 / gsum / gcnt
__global__ void k_scan(int* __restrict__ cnt, int* __restrict__ row_ptr,
                       float* __restrict__ bn_acc3, float* __restrict__ gsum,
                       int* __restrict__ gcnt) {
    __shared__ int wsum[16];
    __shared__ int carry_s;
    int t = threadIdx.x;
    int lane = t & 63, w = t >> 6;
    if (t < 768) bn_acc3[t] = 0.f;
    if (t < 64) { gsum[t] = 0.f; gcnt[t] = 0; }
    if (t == 0) carry_s = 0;
    __syncthreads();
    for (int base = 0; base < NN; base += 4096) {
        int i0 = base + t * 4;
        int v[4];
#pragma unroll
        for (int j = 0; j < 4; j++) v[j] = (i0 + j < NN) ? cnt[i0 + j] : 0;
        int s4 = v[0] + v[1] + v[2] + v[3];
        int s = s4;
#pragma unroll
        for (int o = 1; o < 64; o <<= 1) {
            int u = __shfl_up(s, o);
            if (lane >= o) s += u;
        }
        if (lane == 63) wsum[w] = s;
        __syncthreads();
        if (w == 0) {
            int ws = (lane < 16) ? wsum[lane] : 0;
#pragma unroll
            for (int o = 1; o < 16; o <<= 1) {
                int u = __shfl_up(ws, o);
                if (lane >= o) ws += u;
            }
            if (lane < 16) wsum[lane] = ws;
        }
        __syncthreads();
        int wpre = (w == 0) ? 0 : wsum[w - 1];
        int run = carry_s + wpre + s - s4;
#pragma unroll
        for (int j = 0; j < 4; j++) {
            if (i0 + j < NN) { row_ptr[i0 + j] = run; cnt[i0 + j] = 0; run += v[j]; }
        }
        __syncthreads();
        if (t == 0) carry_s += wsum[15];
        __syncthreads();
    }
    if (t == 0) row_ptr[NN] = carry_s;
}

// ---- GEMM tile body via f16 MFMA: q,xr fp32 out; k,v packed OCP fp8 e4m3 ----
__device__ __forceinline__ void gemm_tile(
    const float* __restrict__ X, const _Float16* __restrict__ wt,
    const float* __restrict__ bq, const float* __restrict__ bk,
    const float* __restrict__ bv, const float* __restrict__ bs,
    const float* ab_s, int use_ab, _Float16 (*xs)[136],
    float* __restrict__ qo, unsigned int* __restrict__ kvb, float* __restrict__ xro,
    int m0)
{
    int t = threadIdx.x;
    int lane = t & 63, wid = t >> 6;
#pragma unroll
    for (int i = 0; i < 8; ++i) {
        int f = t + 256 * i;          // float4 index within 64x32
        int r = f >> 5, c4 = (f & 31) << 2;
        float4 val = make_float4(0.f, 0.f, 0.f, 0.f);
        if (m0 + r < NN) val = *(const float4*)&X[(size_t)(m0 + r) * 128 + c4];
        if (use_ab) {
            float4 a = *(const float4*)&ab_s[c4];
            float4 bb = *(const float4*)&ab_s[128 + c4];
            float z;
            z = fmaf(val.x, a.x, bb.x); val.x = z > 0.f ? z : expm1f(z);
            z = fmaf(val.y, a.y, bb.y); val.y = z > 0.f ? z : expm1f(z);
            z = fmaf(val.z, a.z, bb.z); val.z = z > 0.f ? z : expm1f(z);
            z = fmaf(val.w, a.w, bb.w); val.w = z > 0.f ? z : expm1f(z);
        }
        _Float16* dst = &xs[r][c4];
        dst[0] = (_Float16)val.x; dst[1] = (_Float16)val.y;
        dst[2] = (_Float16)val.z; dst[3] = (_Float16)val.w;
    }
    __syncthreads();
    int quad = lane >> 4, l15 = lane & 15;
    int mrow = wid * 16;
    half8 afrag[4];
#pragma unroll
    for (int kk = 0; kk < 4; kk++)
        afrag[kk] = *(const half8*)&xs[mrow + l15][kk * 32 + quad * 8];

#pragma unroll
    for (int nt = 0; nt < 8; nt++) {
        int c = nt * 16 + l15;
        f32x4 acc[4];
#pragma unroll
        for (int w = 0; w < 4; w++) acc[w] = (f32x4){0.f, 0.f, 0.f, 0.f};
#pragma unroll
        for (int kk = 0; kk < 4; kk++) {
            half8 bf[4];
#pragma unroll
            for (int w = 0; w < 4; w++)
                bf[w] = *(const half8*)&wt[(size_t)w * 16384 + c * 128 + kk * 32 + quad * 8];
#pragma unroll
            for (int w = 0; w < 4; w++)
                acc[w] = __builtin_amdgcn_mfma_f32_16x16x32_f16(afrag[kk], bf[w], acc[w], 0, 0, 0);
        }
        float bqv = bq[c], bkv = bk[c], bvv = bv[c], bsv = bs[c];
        int nodebase = m0 + mrow + quad * 4;
#pragma unroll
        for (int r = 0; r < 4; r++) {
            int node = nodebase + r;
            bool ok = node < NN;
            float qv = acc[0][r] + bqv;
            float xv = acc[3][r] + bsv;
            float kf = acc[1][r] + bkv;
            float vf = acc[2][r] + bvv;
            float kf1 = __shfl_xor(kf, 1);
            float vf1 = __shfl_xor(vf, 1);
            if (ok) {
                qo[(size_t)node * 128 + c] = qv;
                xro[(size_t)node * 128 + c] = xv;
                if (!(lane & 1)) {
                    int w2 = __builtin_amdgcn_cvt_pk_fp8_f32(kf, kf1, 0, false);
                    w2 = __builtin_amdgcn_cvt_pk_fp8_f32(vf, vf1, w2, true);
                    kvb[(size_t)node * 64 + (c >> 1)] = (unsigned int)w2;
                }
            }
        }
    }
}

// ---- layer-0 GEMM fused with CSR scatter (independent work, union grid) ----
__global__ __launch_bounds__(256) void k_gemm0scat(
    const float* __restrict__ X, const _Float16* __restrict__ wt,
    const float* __restrict__ bq, const float* __restrict__ bk,
    const float* __restrict__ bv, const float* __restrict__ bs,
    float* __restrict__ qo, unsigned int* __restrict__ kvb, float* __restrict__ xro,
    const int* __restrict__ eidx, const float* __restrict__ eattr,
    const int* __restrict__ row_ptr, int* __restrict__ cur,
    int* __restrict__ esrc, float* __restrict__ eat2)
{
    __shared__ _Float16 xs[64][136];
    int b = blockIdx.x;
    if (b < GEMM_TILES) {
        gemm_tile(X, wt, bq, bk, bv, bs, nullptr, 0, xs, qo, kvb, xro, b * 64);
    } else {
        int e = (b - GEMM_TILES) * 256 + threadIdx.x;
        if (e < EE) {
            int d = eidx[EE + e];
            int s = eidx[e];
            int p = atomicAdd(&cur[d], 1);
            int pos = row_ptr[d] + p;
            esrc[pos] = s;
            float2 ea = *(const float2*)&eattr[2 * (size_t)e];
            *(float2*)&eat2[2 * (size_t)pos] = ea;
        }
    }
}

// ---- layers 1,2 GEMM (BN affine+ELU on input from bn_acc stats) ----
__global__ __launch_bounds__(256) void k_gemm4(
    const float* __restrict__ X, const _Float16* __restrict__ wt,
    const float* __restrict__ bq, const float* __restrict__ bk,
    const float* __restrict__ bv, const float* __restrict__ bs,
    const float* __restrict__ bn_acc, const float* __restrict__ gamma,
    const float* __restrict__ beta,
    float* __restrict__ qo, unsigned int* __restrict__ kvb, float* __restrict__ xro)
{
    __shared__ _Float16 xs[64][136];
    __shared__ float ab_s[256];
    int t = threadIdx.x;
    if (t < 128) {
        float mu = bn_acc[t] * (1.f / NN);
        float var = bn_acc[128 + t] * (1.f / NN) - mu * mu;
        float inv = rsqrtf(var + 1e-5f);
        float a = inv * gamma[t];
        ab_s[t] = a;
        ab_s[128 + t] = beta[t] - mu * a;
    }
    __syncthreads();
    gemm_tile(X, wt, bq, bk, bv, bs, ab_s, 1, xs, qo, kvb, xro, blockIdx.x * 64);
}

// 16-lane (per-head) sum via DPP row rotations — VALU-only, no DS-pipe ops.
__device__ __forceinline__ float row_sum16(float p) {
    p += __int_as_float(__builtin_amdgcn_update_dpp(0, __float_as_int(p), 0x128, 0xF, 0xF, true)); // row_ror:8
    p += __int_as_float(__builtin_amdgcn_update_dpp(0, __float_as_int(p), 0x124, 0xF, 0xF, true)); // row_ror:4
    p += __int_as_float(__builtin_amdgcn_update_dpp(0, __float_as_int(p), 0x122, 0xF, 0xF, true)); // row_ror:2
    p += __int_as_float(__builtin_amdgcn_update_dpp(0, __float_as_int(p), 0x121, 0xF, 0xF, true)); // row_ror:1
    return p;
}

// ---------------- attention + gate + BN-stats ----------------
// v5: ONE node per wave (50000 waves = 12500 blocks x 4) -> 4x thread-level
// parallelism, per-wave serial chain cut to ~1 round of 16 batched gathers
// (most nodes deg<=16). LDS-staged edge records per wave (coalesced), 16-slot
// rounds fenced with one sched_barrier(0) so all 16 gathers issue before any
// consumer. kk[16] + ~40 state stays well under default VGPR budget: no cap,
// no spill (v4 lesson: 64-reg batch under a 128 cap -> scratch disaster).
__global__ __launch_bounds__(256) void k_attn(
    const float* __restrict__ q, const unsigned int* __restrict__ kvb,
    const float* __restrict__ xr,
    const int* __restrict__ esrc, const float* __restrict__ eat2,
    const int* __restrict__ row_ptr,
    const float* __restrict__ We, const float* __restrict__ be,
    const float* __restrict__ Wb,
    float* __restrict__ out2, float* __restrict__ bn_accum)
{
    __shared__ float4 stage[4][48];   // [wave][slot] = {eax, eay, src<<8 bits, 0}
    int t = threadIdx.x;
    int lane = t & 63;
    int wid = t >> 6;
    int n = blockIdx.x * 4 + wid;          // one node per wave
    int ch = lane * 2;
    float2 we0 = *(const float2*)&We[ch];
    float2 we1 = *(const float2*)&We[128 + ch];
    float2 beL = *(const float2*)&be[ch];
    const float S2 = 0.17677669529663687f * 1.4426950408889634f;  // (1/sqrt(32))*log2(e)

    // wave-uniform row pointers (SGPRs)
    int rs = __builtin_amdgcn_readfirstlane(row_ptr[n]);
    int re = __builtin_amdgcn_readfirstlane(row_ptr[n + 1]);
    int deg = re - rs;
    int degC = deg < 48 ? deg : 48;
    int dem1 = degC > 0 ? degC - 1 : 0;

    // coalesced staging of this node's edge records into LDS (lane -> slot)
    for (int b = lane; b < degC; b += 64) {
        int idx = rs + b;
        float2 a = *(const float2*)&eat2[2 * (size_t)idx];
        int s = esrc[idx] << 8;            // byte offset into kvb
        stage[wid][b] = make_float4(a.x, a.y, __int_as_float(s), 0.f);
    }
    // same-wave LDS ops complete in order: no barrier needed.

    // q row (pre-scaled) + folded edge-projection coefficients
    float2 qv0 = *(const float2*)&q[(size_t)n * 128 + ch];
    float2 qs; qs.x = qv0.x * S2; qs.y = qv0.y * S2;
    float qw0 = qs.x * we0.x + qs.y * we0.y;
    float qw1 = qs.x * we1.x + qs.y * we1.y;
    float qb0 = qs.x * beL.x + qs.y * beL.y;

    float den = 0.f, sA = 0.f, sB = 0.f, ax = 0.f, ay = 0.f;
    const char* kvb8 = (const char*)kvb;
    int lb = lane << 2;

    int rmax = (degC + 15) >> 4;
    for (int r = 0; r < rmax; ++r) {
        int b0 = r * 16;
        unsigned int kk[16];
        // issue phase: 16 batched kvb row gathers (addresses from uniform ds_read)
#pragma unroll
        for (int j = 0; j < 16; j++) {
            int o = b0 + j;
            int oc = o < dem1 ? o : dem1;
            int sv = __float_as_int(stage[wid][oc].z);
            kk[j] = *(const unsigned int*)(kvb8 + sv + lb);
        }
        __builtin_amdgcn_sched_barrier(0);
        // compute phase
#pragma unroll
        for (int j = 0; j < 16; j++) {
            int o = b0 + j;
            int oc = o < dem1 ? o : dem1;
            float2 aa = *(const float2*)&stage[wid][oc];
            unsigned int w8 = kk[j];
            auto kf = __builtin_amdgcn_cvt_pk_f32_fp8((int)w8, false);
            auto vf = __builtin_amdgcn_cvt_pk_f32_fp8((int)w8, true);
            float p = qs.x * kf[0];
            p = fmaf(qs.y, kf[1], p);
            p = fmaf(aa.x, qw0, p);
            p = fmaf(aa.y, qw1, p);
            p += qb0;
            p = row_sum16(p);
            float ex = (o < degC) ? __builtin_amdgcn_exp2f(p) : 0.f;
            den += ex;
            sA = fmaf(ex, aa.x, sA);
            sB = fmaf(ex, aa.y, sB);
            ax = fmaf(ex, vf[0], ax);
            ay = fmaf(ex, vf[1], ay);
        }
    }

    // scalar fallback for degree > 48 (correctness only; ~never taken)
    if (deg > 48) {
        for (int m = rs + 48; m < re; ++m) {
            int s0 = __builtin_amdgcn_readfirstlane(esrc[m]);
            float2 aa = *(const float2*)&eat2[2 * (size_t)m];
            unsigned int w8 = *(const unsigned int*)(kvb8 + ((size_t)(unsigned)s0 << 8) + lb);
            auto kf = __builtin_amdgcn_cvt_pk_f32_fp8((int)w8, false);
            auto vf = __builtin_amdgcn_cvt_pk_f32_fp8((int)w8, true);
            float p = qs.x * kf[0];
            p = fmaf(qs.y, kf[1], p);
            p = fmaf(aa.x, qw0, p);
            p = fmaf(aa.y, qw1, p);
            p += qb0;
            p = row_sum16(p);
            float ex = __builtin_amdgcn_exp2f(p);
            den += ex;
            sA = fmaf(ex, aa.x, sA);
            sB = fmaf(ex, aa.y, sB);
            ax = fmaf(ex, vf[0], ax);
            ay = fmaf(ex, vf[1], ay);
        }
    }

    // finish: fold Σw·e back in, beta gate + store + BN partials
    float2 wb_o = *(const float2*)&Wb[ch];
    float2 wb_r = *(const float2*)&Wb[128 + ch];
    float2 wb_d = *(const float2*)&Wb[256 + ch];
    float2 xv = *(const float2*)&xr[(size_t)n * 128 + ch];
    float axT = ax + sA * we0.x + sB * we1.x + den * beL.x;
    float ayT = ay + sA * we0.y + sB * we1.y + den * beL.y;
    float rden = 1.f / (den + 1e-16f);
    float axs = axT * rden, ays = ayT * rden;
    float gp = axs * wb_o.x + ays * wb_o.y + xv.x * wb_r.x + xv.y * wb_r.y
             + (axs - xv.x) * wb_d.x + (ays - xv.y) * wb_d.y;
    gp = row_sum16(gp);
    gp += __shfl_xor(gp, 16);
    gp += __shfl_xor(gp, 32);
    float gate = 1.f / (1.f + __expf(-gp));
    float ox = gate * xv.x + (1.f - gate) * axs;
    float oy = gate * xv.y + (1.f - gate) * ays;
    *(float2*)&out2[(size_t)n * 128 + ch] = make_float2(ox, oy);

    // block-level BN partial reduce
    __shared__ float s_sum[2][256], s_sq[2][256];
    s_sum[0][t] = ox; s_sum[1][t] = oy;
    s_sq[0][t] = ox * ox;  s_sq[1][t] = oy * oy;
    __syncthreads();
    if (t < 64) {
        float sx = s_sum[0][t] + s_sum[0][64 + t] + s_sum[0][128 + t] + s_sum[0][192 + t];
        float sy = s_sum[1][t] + s_sum[1][64 + t] + s_sum[1][128 + t] + s_sum[1][192 + t];
        float qx = s_sq[0][t] + s_sq[0][64 + t] + s_sq[0][128 + t] + s_sq[0][192 + t];
        float qy = s_sq[1][t] + s_sq[1][64 + t] + s_sq[1][128 + t] + s_sq[1][192 + t];
        int c = 2 * t;
        atomicAdd(&bn_accum[c], sx);
        atomicAdd(&bn_accum[c + 1], sy);
        atomicAdd(&bn_accum[128 + c], qx);
        atomicAdd(&bn_accum[128 + c + 1], qy);
    }
}

// ------- readout: BN affine+ELU+dot(Wout), 4 prefetched loads/wave, LDS per-graph
//         accumulate, one flush per block -------
__global__ __launch_bounds__(256) void k_pool(const float* __restrict__ x,
                                              const float* __restrict__ bn_acc,
                                              const float* __restrict__ gamma,
                                              const float* __restrict__ beta,
                                              const float* __restrict__ Wout,
                                              const int* __restrict__ batch,
                                              float* __restrict__ gsum, int* __restrict__ gcnt) {
    __shared__ float lsum[NGRAPH];
    __shared__ int lcnt[NGRAPH];
    __shared__ float ab_s[256];
    int t = threadIdx.x;
    if (t < NGRAPH) { lsum[t] = 0.f; lcnt[t] = 0; }
    if (t < 128) {
        float mu = bn_acc[t] * (1.f / NN);
        float var = bn_acc[128 + t] * (1.f / NN) - mu * mu;
        float inv = rsqrtf(var + 1e-5f);
        float a = inv * gamma[t];
        ab_s[t] = a;
        ab_s[128 + t] = beta[t] - mu * a;
    }
    __syncthreads();
    int lane = t & 63;
    int wid = t >> 6;
    int ch = lane * 2;
    float2 wo = *(const float2*)&Wout[ch];
    float2 a = *(const float2*)&ab_s[ch];
    float2 b = *(const float2*)&ab_s[128 + ch];
    int base = blockIdx.x * 16 + wid * 4;
    float2 xv[4];
#pragma unroll
    for (int i = 0; i < 4; i++) {          // issue all 4 loads before any use
        int n = base + i;
        xv[i] = (n < NN) ? *(const float2*)&x[(size_t)n * 128 + ch]
                         : make_float2(0.f, 0.f);
    }
#pragma unroll
    for (int i = 0; i < 4; i++) {
        int n = base + i;
        if (n < NN) {
            float z0 = fmaf(xv[i].x, a.x, b.x); z0 = z0 > 0.f ? z0 : expm1f(z0);
            float z1 = fmaf(xv[i].y, a.y, b.y); z1 = z1 > 0.f ? z1 : expm1f(z1);
            float p = z0 * wo.x + z1 * wo.y;
            p += __shfl_xor(p, 1);
            p += __shfl_xor(p, 2);
            p += __shfl_xor(p, 4);
            p += __shfl_xor(p, 8);
            p += __shfl_xor(p, 16);
            p += __shfl_xor(p, 32);
            if (lane == 0) {
                int g = batch[n];
                atomicAdd(&lsum[g], p);
                atomicAdd(&lcnt[g], 1);
            }
        }
    }
    __syncthreads();
    if (t < NGRAPH && lcnt[t] > 0) {
        atomicAdd(&gsum[t], lsum[t]);
        atomicAdd(&gcnt[t], lcnt[t]);
    }
}

__global__ void k_final(const float* __restrict__ gsum, const int* __restrict__ gcnt,
                        const float* __restrict__ bout, const float* __restrict__ obias,
                        float* __restrict__ out) {
    int g = threadIdx.x;
    if (g < NGRAPH) out[g] = gsum[g] / fmaxf((float)gcnt[g], 1.f) + bout[0] + obias[0];
}

extern "C" void kernel_launch(void* const* d_in, const int* in_sizes, int n_in,
                              void* d_out, int out_size, void* d_ws, size_t ws_size,
                              hipStream_t stream) {
    const float* x_in       = (const float*)d_in[0];
    const int* eidx         = (const int*)d_in[1];
    const float* eattr      = (const float*)d_in[2];
    const int* batch        = (const int*)d_in[3];
    const float* Wq         = (const float*)d_in[4];
    const float* bq         = (const float*)d_in[5];
    const float* Wk         = (const float*)d_in[6];
    const float* bk         = (const float*)d_in[7];
    const float* Wv         = (const float*)d_in[8];
    const float* bv         = (const float*)d_in[9];
    const float* We         = (const float*)d_in[10];
    const float* be         = (const float*)d_in[11];
    const float* Wskip      = (const float*)d_in[12];
    const float* bskip      = (const float*)d_in[13];
    const float* Wbeta      = (const float*)d_in[14];
    const float* bn_gamma   = (const float*)d_in[15];
    const float* bn_beta    = (const float*)d_in[16];
    const float* Wout       = (const float*)d_in[17];
    const float* bout       = (const float*)d_in[18];
    const float* obias      = (const float*)d_in[19];
    float* out = (float*)d_out;

    char* ws = (char*)d_ws;
    size_t off = 0;
    auto alloc = [&](size_t bytes) -> void* {
        off = (off + 255) & ~(size_t)255;
        void* p = ws + off;
        off += bytes;
        return p;
    };
    const size_t NF = (size_t)NN * 128 * sizeof(float);
    float* xbuf    = (float*)alloc(NF);
    float* qb      = (float*)alloc(NF);
    float* xrb     = (float*)alloc(NF);
    unsigned int* kvb = (unsigned int*)alloc((size_t)NN * 64 * sizeof(unsigned int));
    _Float16* wt   = (_Float16*)alloc((size_t)12 * 16384 * sizeof(_Float16));
    int* row_ptr   = (int*)alloc((NN + 1) * sizeof(int));
    int* cnt       = (int*)alloc(NN * sizeof(int));
    int* esrc      = (int*)alloc(EE * sizeof(int));
    float* eat2    = (float*)alloc((size_t)EE * 2 * sizeof(float));
    float* bn_acc3 = (float*)alloc(3 * 256 * sizeof(float));
    float* gsum    = (float*)alloc(64 * sizeof(float));
    int* gcnt      = (int*)alloc(64 * sizeof(int));
    (void)ws_size; (void)n_in; (void)in_sizes; (void)out_size;

    // ---- CSR degree + weight prep, scan (also zeroes aux) ----
    hipMemsetAsync(cnt, 0, NN * sizeof(int), stream);
    k_degprep<<<3125 + 768, 256, 0, stream>>>(eidx, cnt, Wq, Wk, Wv, Wskip, wt);
    k_scan<<<1, 1024, 0, stream>>>(cnt, row_ptr, bn_acc3, gsum, gcnt);

    // ---- layer 0 GEMM + CSR scatter fused (independent work) ----
    k_gemm0scat<<<GEMM_TILES + 3125, 256, 0, stream>>>(
        x_in, wt, bq, bk, bv, bskip, qb, kvb, xrb,
        eidx, eattr, row_ptr, cnt, esrc, eat2);
    k_attn<<<12500, 256, 0, stream>>>(
        qb, kvb, xrb, esrc, eat2, row_ptr,
        We, be, Wbeta, xbuf, bn_acc3);

    // ---- layers 1,2 ----
    for (int l = 1; l < 3; ++l) {
        k_gemm4<<<GEMM_TILES, 256, 0, stream>>>(
            xbuf, wt + (size_t)l * 65536,
            bq + l * 128, bk + l * 128, bv + l * 128, bskip + l * 128,
            bn_acc3 + (l - 1) * 256, bn_gamma + (l - 1) * 128, bn_beta + (l - 1) * 128,
            qb, kvb, xrb);
        k_attn<<<12500, 256, 0, stream>>>(
            qb, kvb, xrb, esrc, eat2, row_ptr,
            We + (size_t)l * 256, be + l * 128, Wbeta + (size_t)l * 384,
            xbuf, bn_acc3 + l * 256);
    }

    // ---- readout (BN affine+ELU of layer-2 fused in) ----
    k_pool<<<(NN + 15) / 16, 256, 0, stream>>>(xbuf, bn_acc3 + 2 * 256,
                                               bn_gamma + 2 * 128, bn_beta + 2 * 128,
                                               Wout, batch, gsum, gcnt);
    k_final<<<1, 64, 0, stream>>>(gsum, gcnt, bout, obias, out);
}

// Round 5
// 716.012 us; speedup vs baseline: 3.1672x; 3.1672x over previous
//
#include <hip/hip_runtime.h>
#include <hip/hip_fp16.h>
#include <math.h>

#define NN 50000
#define EE 800000
#define HIDDEN 128
#define NGRAPH 50
#define GEMM_TILES ((NN + 63) / 64)
#define NB_ATTN 3125

typedef _Float16 half8 __attribute__((ext_vector_type(8)));
typedef float f32x4 __attribute__((ext_vector_type(4)));

// ---------------- CSR degree count + weight transpose (union grid) ----------------
__global__ void k_degprep(const int* __restrict__ eidx, int* __restrict__ cnt,
                          const float* __restrict__ Wq, const float* __restrict__ Wk,
                          const float* __restrict__ Wv, const float* __restrict__ Ws,
                          _Float16* __restrict__ wt) {
    int b = blockIdx.x;
    int t = threadIdx.x;
    if (b < 3125) {
        int e = b * 256 + t;
        if (e < EE) atomicAdd(&cnt[eidx[EE + e]], 1);
    } else {
        int idx = (b - 3125) * 256 + t;   // 12 * 16384 fp16 transposed weights
        if (idx < 12 * 16384) {
            int mat = idx >> 14;
            int l = mat >> 2, w = mat & 3;
            int nk = idx & 16383;
            int n = nk >> 7, k = nk & 127;
            const float* W = (w == 0 ? Wq : w == 1 ? Wk : w == 2 ? Wv : Ws) + (size_t)l * 16384;
            wt[idx] = (_Float16)W[k * 128 + n];
        }
    }
}

// scan + housekeeping: exclusive-scan deg->row_ptr (4 elems/thread), zero cnt,
// zero bn_acc3 / gsum / gcnt
__global__ void k_scan(int* __restrict__ cnt, int* __restrict__ row_ptr,
                       float* __restrict__ bn_acc3, float* __restrict__ gsum,
                       int* __restrict__ gcnt) {
    __shared__ int wsum[16];
    __shared__ int carry_s;
    int t = threadIdx.x;
    int lane = t & 63, w = t >> 6;
    if (t < 768) bn_acc3[t] = 0.f;
    if (t < 64) { gsum[t] = 0.f; gcnt[t] = 0; }
    if (t == 0) carry_s = 0;
    __syncthreads();
    for (int base = 0; base < NN; base += 4096) {
        int i0 = base + t * 4;
        int v[4];
#pragma unroll
        for (int j = 0; j < 4; j++) v[j] = (i0 + j < NN) ? cnt[i0 + j] : 0;
        int s4 = v[0] + v[1] + v[2] + v[3];
        int s = s4;
#pragma unroll
        for (int o = 1; o < 64; o <<= 1) {
            int u = __shfl_up(s, o);
            if (lane >= o) s += u;
        }
        if (lane == 63) wsum[w] = s;
        __syncthreads();
        if (w == 0) {
            int ws = (lane < 16) ? wsum[lane] : 0;
#pragma unroll
            for (int o = 1; o < 16; o <<= 1) {
                int u = __shfl_up(ws, o);
                if (lane >= o) ws += u;
            }
            if (lane < 16) wsum[lane] = ws;
        }
        __syncthreads();
        int wpre = (w == 0) ? 0 : wsum[w - 1];
        int run = carry_s + wpre + s - s4;
#pragma unroll
        for (int j = 0; j < 4; j++) {
            if (i0 + j < NN) { row_ptr[i0 + j] = run; cnt[i0 + j] = 0; run += v[j]; }
        }
        __syncthreads();
        if (t == 0) carry_s += wsum[15];
        __syncthreads();
    }
    if (t == 0) row_ptr[NN] = carry_s;
}

// ---- GEMM tile body via f16 MFMA: q,xr fp32 out; k,v packed OCP fp8 e4m3 ----
__device__ __forceinline__ void gemm_tile(
    const float* __restrict__ X, const _Float16* __restrict__ wt,
    const float* __restrict__ bq, const float* __restrict__ bk,
    const float* __restrict__ bv, const float* __restrict__ bs,
    const float* ab_s, int use_ab, _Float16 (*xs)[136],
    float* __restrict__ qo, unsigned int* __restrict__ kvb, float* __restrict__ xro,
    int m0)
{
    int t = threadIdx.x;
    int lane = t & 63, wid = t >> 6;
#pragma unroll
    for (int i = 0; i < 8; ++i) {
        int f = t + 256 * i;          // float4 index within 64x32
        int r = f >> 5, c4 = (f & 31) << 2;
        float4 val = make_float4(0.f, 0.f, 0.f, 0.f);
        if (m0 + r < NN) val = *(const float4*)&X[(size_t)(m0 + r) * 128 + c4];
        if (use_ab) {
            float4 a = *(const float4*)&ab_s[c4];
            float4 bb = *(const float4*)&ab_s[128 + c4];
            float z;
            z = fmaf(val.x, a.x, bb.x); val.x = z > 0.f ? z : expm1f(z);
            z = fmaf(val.y, a.y, bb.y); val.y = z > 0.f ? z : expm1f(z);
            z = fmaf(val.z, a.z, bb.z); val.z = z > 0.f ? z : expm1f(z);
            z = fmaf(val.w, a.w, bb.w); val.w = z > 0.f ? z : expm1f(z);
        }
        _Float16* dst = &xs[r][c4];
        dst[0] = (_Float16)val.x; dst[1] = (_Float16)val.y;
        dst[2] = (_Float16)val.z; dst[3] = (_Float16)val.w;
    }
    __syncthreads();
    int quad = lane >> 4, l15 = lane & 15;
    int mrow = wid * 16;
    half8 afrag[4];
#pragma unroll
    for (int kk = 0; kk < 4; kk++)
        afrag[kk] = *(const half8*)&xs[mrow + l15][kk * 32 + quad * 8];

#pragma unroll
    for (int nt = 0; nt < 8; nt++) {
        int c = nt * 16 + l15;
        f32x4 acc[4];
#pragma unroll
        for (int w = 0; w < 4; w++) acc[w] = (f32x4){0.f, 0.f, 0.f, 0.f};
#pragma unroll
        for (int kk = 0; kk < 4; kk++) {
            half8 bf[4];
#pragma unroll
            for (int w = 0; w < 4; w++)
                bf[w] = *(const half8*)&wt[(size_t)w * 16384 + c * 128 + kk * 32 + quad * 8];
#pragma unroll
            for (int w = 0; w < 4; w++)
                acc[w] = __builtin_amdgcn_mfma_f32_16x16x32_f16(afrag[kk], bf[w], acc[w], 0, 0, 0);
        }
        float bqv = bq[c], bkv = bk[c], bvv = bv[c], bsv = bs[c];
        int nodebase = m0 + mrow + quad * 4;
#pragma unroll
        for (int r = 0; r < 4; r++) {
            int node = nodebase + r;
            bool ok = node < NN;
            float qv = acc[0][r] + bqv;
            float xv = acc[3][r] + bsv;
            float kf = acc[1][r] + bkv;
            float vf = acc[2][r] + bvv;
            float kf1 = __shfl_xor(kf, 1);
            float vf1 = __shfl_xor(vf, 1);
            if (ok) {
                qo[(size_t)node * 128 + c] = qv;
                xro[(size_t)node * 128 + c] = xv;
                if (!(lane & 1)) {
                    int w2 = __builtin_amdgcn_cvt_pk_fp8_f32(kf, kf1, 0, false);
                    w2 = __builtin_amdgcn_cvt_pk_fp8_f32(vf, vf1, w2, true);
                    kvb[(size_t)node * 64 + (c >> 1)] = (unsigned int)w2;
                }
            }
        }
    }
}

// ---- layer-0 GEMM fused with CSR scatter (independent work, union grid) ----
__global__ __launch_bounds__(256) void k_gemm0scat(
    const float* __restrict__ X, const _Float16* __restrict__ wt,
    const float* __restrict__ bq, const float* __restrict__ bk,
    const float* __restrict__ bv, const float* __restrict__ bs,
    float* __restrict__ qo, unsigned int* __restrict__ kvb, float* __restrict__ xro,
    const int* __restrict__ eidx, const float* __restrict__ eattr,
    const int* __restrict__ row_ptr, int* __restrict__ cur,
    int* __restrict__ esrc, float* __restrict__ eat2)
{
    __shared__ _Float16 xs[64][136];
    int b = blockIdx.x;
    if (b < GEMM_TILES) {
        gemm_tile(X, wt, bq, bk, bv, bs, nullptr, 0, xs, qo, kvb, xro, b * 64);
    } else {
        int e = (b - GEMM_TILES) * 256 + threadIdx.x;
        if (e < EE) {
            int d = eidx[EE + e];
            int s = eidx[e];
            int p = atomicAdd(&cur[d], 1);
            int pos = row_ptr[d] + p;
            esrc[pos] = s;
            float2 ea = *(const float2*)&eattr[2 * (size_t)e];
            *(float2*)&eat2[2 * (size_t)pos] = ea;
        }
    }
}

// ---- layers 1,2 GEMM (BN affine+ELU on input from bn_acc stats) ----
__global__ __launch_bounds__(256) void k_gemm4(
    const float* __restrict__ X, const _Float16* __restrict__ wt,
    const float* __restrict__ bq, const float* __restrict__ bk,
    const float* __restrict__ bv, const float* __restrict__ bs,
    const float* __restrict__ bn_acc, const float* __restrict__ gamma,
    const float* __restrict__ beta,
    float* __restrict__ qo, unsigned int* __restrict__ kvb, float* __restrict__ xro)
{
    __shared__ _Float16 xs[64][136];
    __shared__ float ab_s[256];
    int t = threadIdx.x;
    if (t < 128) {
        float mu = bn_acc[t] * (1.f / NN);
        float var = bn_acc[128 + t] * (1.f / NN) - mu * mu;
        float inv = rsqrtf(var + 1e-5f);
        float a = inv * gamma[t];
        ab_s[t] = a;
        ab_s[128 + t] = beta[t] - mu * a;
    }
    __syncthreads();
    gemm_tile(X, wt, bq, bk, bv, bs, ab_s, 1, xs, qo, kvb, xro, blockIdx.x * 64);
}

// ---------------- attention + gate + BN-stats (one wave per dst node) ----------------
// v6 = v1 core (r10-exact structure, best measured): cooperative lane-load of CSR
// src/attr, groups of 8 fp8 kv gathers in flight + scalar tail. ONLY change:
// the BN reduction tail writes per-block partials (contention-free stores)
// instead of 256 same-address atomicAdds per block — R4 diagnosis showed the
// contended atomics, not the gathers, were the ~150us floor.
__global__ __launch_bounds__(256) void k_attn(
    const float* __restrict__ q, const unsigned int* __restrict__ kvb,
    const float* __restrict__ xr,
    const int* __restrict__ esrc, const float* __restrict__ eat2,
    const int* __restrict__ row_ptr,
    const float* __restrict__ We, const float* __restrict__ be,
    const float* __restrict__ Wb,
    float* __restrict__ out2, float* __restrict__ bnp)
{
    int t = threadIdx.x;
    int lane = t & 63;
    int wid = t >> 6;
    int gwave = blockIdx.x * 4 + wid;
    int nwaves = gridDim.x * 4;
    int ch = lane * 2;
    float2 we0 = *(const float2*)&We[ch];
    float2 we1 = *(const float2*)&We[128 + ch];
    float2 beL = *(const float2*)&be[ch];
    float2 wb_o = *(const float2*)&Wb[ch];
    float2 wb_r = *(const float2*)&Wb[128 + ch];
    float2 wb_d = *(const float2*)&Wb[256 + ch];
    const float scale = 0.17677669529663687f;   // 1/sqrt(32)
    float bnsx = 0.f, bnsy = 0.f, bnqx = 0.f, bnqy = 0.f;

    for (int n = gwave; n < NN; n += nwaves) {
        int rs = __builtin_amdgcn_readfirstlane(row_ptr[n]);
        int re = __builtin_amdgcn_readfirstlane(row_ptr[n + 1]);
        float2 qv = *(const float2*)&q[(size_t)n * 128 + ch];
        float den = 0.f;
        float ax = 0.f, ay = 0.f;

        auto edge = [&](float eax, float eay, unsigned int w8) {
            auto kf = __builtin_amdgcn_cvt_pk_f32_fp8((int)w8, false);
            auto vf = __builtin_amdgcn_cvt_pk_f32_fp8((int)w8, true);
            float ex_ = fmaf(eax, we0.x, fmaf(eay, we1.x, beL.x));
            float ey_ = fmaf(eax, we0.y, fmaf(eay, we1.y, beL.y));
            float p = qv.x * (kf[0] + ex_) + qv.y * (kf[1] + ey_);
            p += __shfl_xor(p, 1);
            p += __shfl_xor(p, 2);
            p += __shfl_xor(p, 4);
            p += __shfl_xor(p, 8);
            float exv = __expf(p * scale);
            den += exv;
            ax = fmaf(exv, vf[0] + ex_, ax);
            ay = fmaf(exv, vf[1] + ey_, ay);
        };

        for (int cb = rs; cb < re; cb += 64) {
            int cnum = re - cb; if (cnum > 64) cnum = 64;
            int mi = cb + lane;
            int sv = 0;
            float2 av = make_float2(0.f, 0.f);
            if (mi < re) {
                sv = esrc[mi];
                av = *(const float2*)&eat2[2 * (size_t)mi];
            }
            int base = 0;
            for (; base + 8 <= cnum; base += 8) {
                int s[8]; float eax[8], eay[8];
#pragma unroll
                for (int j = 0; j < 8; j++) {
                    s[j] = __shfl(sv, base + j);
                    eax[j] = __shfl(av.x, base + j);
                    eay[j] = __shfl(av.y, base + j);
                }
                unsigned int kk[8];
#pragma unroll
                for (int j = 0; j < 8; j++)
                    kk[j] = kvb[(size_t)s[j] * 64 + lane];
#pragma unroll
                for (int j = 0; j < 8; j++) edge(eax[j], eay[j], kk[j]);
            }
            for (; base < cnum; ++base) {
                int s0 = __shfl(sv, base);
                float ex0 = __shfl(av.x, base);
                float ey0 = __shfl(av.y, base);
                unsigned int k0 = kvb[(size_t)s0 * 64 + lane];
                edge(ex0, ey0, k0);
            }
        }

        float rden = 1.f / (den + 1e-16f);
        ax *= rden; ay *= rden;
        // beta gate
        float2 xv = *(const float2*)&xr[(size_t)n * 128 + ch];
        float gp = ax * wb_o.x + ay * wb_o.y + xv.x * wb_r.x + xv.y * wb_r.y
                 + (ax - xv.x) * wb_d.x + (ay - xv.y) * wb_d.y;
        gp += __shfl_xor(gp, 1);
        gp += __shfl_xor(gp, 2);
        gp += __shfl_xor(gp, 4);
        gp += __shfl_xor(gp, 8);
        gp += __shfl_xor(gp, 16);
        gp += __shfl_xor(gp, 32);
        float gate = 1.f / (1.f + __expf(-gp));
        float ox = gate * xv.x + (1.f - gate) * ax;
        float oy = gate * xv.y + (1.f - gate) * ay;
        *(float2*)&out2[(size_t)n * 128 + ch] = make_float2(ox, oy);
        bnsx += ox; bnsy += oy;
        bnqx = fmaf(ox, ox, bnqx); bnqy = fmaf(oy, oy, bnqy);
    }
    // block-level BN partial reduce -> contention-free per-block slots
    __shared__ float s_sum[2][256], s_sq[2][256];
    s_sum[0][t] = bnsx; s_sum[1][t] = bnsy;
    s_sq[0][t] = bnqx;  s_sq[1][t] = bnqy;
    __syncthreads();
    if (t < 64) {
        float sx = s_sum[0][t] + s_sum[0][64 + t] + s_sum[0][128 + t] + s_sum[0][192 + t];
        float sy = s_sum[1][t] + s_sum[1][64 + t] + s_sum[1][128 + t] + s_sum[1][192 + t];
        float qx = s_sq[0][t] + s_sq[0][64 + t] + s_sq[0][128 + t] + s_sq[0][192 + t];
        float qy = s_sq[1][t] + s_sq[1][64 + t] + s_sq[1][128 + t] + s_sq[1][192 + t];
        int c = 2 * t;
        int b = blockIdx.x;
        bnp[(size_t)c * NB_ATTN + b]         = sx;
        bnp[(size_t)(c + 1) * NB_ATTN + b]   = sy;
        bnp[(size_t)(128 + c) * NB_ATTN + b] = qx;
        bnp[(size_t)(129 + c) * NB_ATTN + b] = qy;
    }
}

// ---- reduce per-block BN partials -> bn_acc (one block per channel slot) ----
__global__ __launch_bounds__(256) void k_bnred(const float* __restrict__ part,
                                               float* __restrict__ bn_acc) {
    __shared__ float red[256];
    int chs = blockIdx.x, t = threadIdx.x;
    const float* p = part + (size_t)chs * NB_ATTN;
    float s = 0.f;
    for (int i = t; i < NB_ATTN; i += 256) s += p[i];
    red[t] = s;
    __syncthreads();
    if (t < 128) red[t] += red[t + 128];
    __syncthreads();
    if (t < 64) {
        float v = red[t] + red[t + 64];
        v += __shfl_down(v, 32);
        v += __shfl_down(v, 16);
        v += __shfl_down(v, 8);
        v += __shfl_down(v, 4);
        v += __shfl_down(v, 2);
        v += __shfl_down(v, 1);
        if (t == 0) bn_acc[chs] = v;
    }
}

// ------- readout: BN affine+ELU+dot(Wout); 313 blocks x 10 chunks to keep
//         gsum/gcnt atomic contention low; LDS per-graph accumulate, one flush -------
__global__ __launch_bounds__(256) void k_pool(const float* __restrict__ x,
                                              const float* __restrict__ bn_acc,
                                              const float* __restrict__ gamma,
                                              const float* __restrict__ beta,
                                              const float* __restrict__ Wout,
                                              const int* __restrict__ batch,
                                              float* __restrict__ gsum, int* __restrict__ gcnt) {
    __shared__ float lsum[NGRAPH];
    __shared__ int lcnt[NGRAPH];
    __shared__ float ab_s[256];
    int t = threadIdx.x;
    if (t < NGRAPH) { lsum[t] = 0.f; lcnt[t] = 0; }
    if (t < 128) {
        float mu = bn_acc[t] * (1.f / NN);
        float var = bn_acc[128 + t] * (1.f / NN) - mu * mu;
        float inv = rsqrtf(var + 1e-5f);
        float a = inv * gamma[t];
        ab_s[t] = a;
        ab_s[128 + t] = beta[t] - mu * a;
    }
    __syncthreads();
    int lane = t & 63;
    int wid = t >> 6;
    int ch = lane * 2;
    float2 wo = *(const float2*)&Wout[ch];
    float2 a = *(const float2*)&ab_s[ch];
    float2 b = *(const float2*)&ab_s[128 + ch];
    for (int chunk = 0; chunk < 10; ++chunk) {
        int base = blockIdx.x * 160 + chunk * 16 + wid * 4;
        float2 xv[4];
#pragma unroll
        for (int i = 0; i < 4; i++) {          // issue all 4 loads before any use
            int n = base + i;
            xv[i] = (n < NN) ? *(const float2*)&x[(size_t)n * 128 + ch]
                             : make_float2(0.f, 0.f);
        }
#pragma unroll
        for (int i = 0; i < 4; i++) {
            int n = base + i;
            if (n < NN) {
                float z0 = fmaf(xv[i].x, a.x, b.x); z0 = z0 > 0.f ? z0 : expm1f(z0);
                float z1 = fmaf(xv[i].y, a.y, b.y); z1 = z1 > 0.f ? z1 : expm1f(z1);
                float p = z0 * wo.x + z1 * wo.y;
                p += __shfl_xor(p, 1);
                p += __shfl_xor(p, 2);
                p += __shfl_xor(p, 4);
                p += __shfl_xor(p, 8);
                p += __shfl_xor(p, 16);
                p += __shfl_xor(p, 32);
                if (lane == 0) {
                    int g = batch[n];
                    atomicAdd(&lsum[g], p);
                    atomicAdd(&lcnt[g], 1);
                }
            }
        }
    }
    __syncthreads();
    if (t < NGRAPH && lcnt[t] > 0) {
        atomicAdd(&gsum[t], lsum[t]);
        atomicAdd(&gcnt[t], lcnt[t]);
    }
}

__global__ void k_final(const float* __restrict__ gsum, const int* __restrict__ gcnt,
                        const float* __restrict__ bout, const float* __restrict__ obias,
                        float* __restrict__ out) {
    int g = threadIdx.x;
    if (g < NGRAPH) out[g] = gsum[g] / fmaxf((float)gcnt[g], 1.f) + bout[0] + obias[0];
}

extern "C" void kernel_launch(void* const* d_in, const int* in_sizes, int n_in,
                              void* d_out, int out_size, void* d_ws, size_t ws_size,
                              hipStream_t stream) {
    const float* x_in       = (const float*)d_in[0];
    const int* eidx         = (const int*)d_in[1];
    const float* eattr      = (const float*)d_in[2];
    const int* batch        = (const int*)d_in[3];
    const float* Wq         = (const float*)d_in[4];
    const float* bq         = (const float*)d_in[5];
    const float* Wk         = (const float*)d_in[6];
    const float* bk         = (const float*)d_in[7];
    const float* Wv         = (const float*)d_in[8];
    const float* bv         = (const float*)d_in[9];
    const float* We         = (const float*)d_in[10];
    const float* be         = (const float*)d_in[11];
    const float* Wskip      = (const float*)d_in[12];
    const float* bskip      = (const float*)d_in[13];
    const float* Wbeta      = (const float*)d_in[14];
    const float* bn_gamma   = (const float*)d_in[15];
    const float* bn_beta    = (const float*)d_in[16];
    const float* Wout       = (const float*)d_in[17];
    const float* bout       = (const float*)d_in[18];
    const float* obias      = (const float*)d_in[19];
    float* out = (float*)d_out;

    char* ws = (char*)d_ws;
    size_t off = 0;
    auto alloc = [&](size_t bytes) -> void* {
        off = (off + 255) & ~(size_t)255;
        void* p = ws + off;
        off += bytes;
        return p;
    };
    const size_t NF = (size_t)NN * 128 * sizeof(float);
    float* xbuf    = (float*)alloc(NF);
    float* qb      = (float*)alloc(NF);
    float* xrb     = (float*)alloc(NF);
    unsigned int* kvb = (unsigned int*)alloc((size_t)NN * 64 * sizeof(unsigned int));
    _Float16* wt   = (_Float16*)alloc((size_t)12 * 16384 * sizeof(_Float16));
    int* row_ptr   = (int*)alloc((NN + 1) * sizeof(int));
    int* cnt       = (int*)alloc(NN * sizeof(int));
    int* esrc      = (int*)alloc(EE * sizeof(int));
    float* eat2    = (float*)alloc((size_t)EE * 2 * sizeof(float));
    float* bn_acc3 = (float*)alloc(3 * 256 * sizeof(float));
    float* bnpart  = (float*)alloc((size_t)256 * NB_ATTN * sizeof(float));
    float* gsum    = (float*)alloc(64 * sizeof(float));
    int* gcnt      = (int*)alloc(64 * sizeof(int));
    (void)ws_size; (void)n_in; (void)in_sizes; (void)out_size;

    // ---- CSR degree + weight prep, scan (also zeroes aux) ----
    hipMemsetAsync(cnt, 0, NN * sizeof(int), stream);
    k_degprep<<<3125 + 768, 256, 0, stream>>>(eidx, cnt, Wq, Wk, Wv, Wskip, wt);
    k_scan<<<1, 1024, 0, stream>>>(cnt, row_ptr, bn_acc3, gsum, gcnt);

    // ---- layer 0 GEMM + CSR scatter fused (independent work) ----
    k_gemm0scat<<<GEMM_TILES + 3125, 256, 0, stream>>>(
        x_in, wt, bq, bk, bv, bskip, qb, kvb, xrb,
        eidx, eattr, row_ptr, cnt, esrc, eat2);
    k_attn<<<NB_ATTN, 256, 0, stream>>>(
        qb, kvb, xrb, esrc, eat2, row_ptr,
        We, be, Wbeta, xbuf, bnpart);
    k_bnred<<<256, 256, 0, stream>>>(bnpart, bn_acc3);

    // ---- layers 1,2 ----
    for (int l = 1; l < 3; ++l) {
        k_gemm4<<<GEMM_TILES, 256, 0, stream>>>(
            xbuf, wt + (size_t)l * 65536,
            bq + l * 128, bk + l * 128, bv + l * 128, bskip + l * 128,
            bn_acc3 + (l - 1) * 256, bn_gamma + (l - 1) * 128, bn_beta + (l - 1) * 128,
            qb, kvb, xrb);
        k_attn<<<NB_ATTN, 256, 0, stream>>>(
            qb, kvb, xrb, esrc, eat2, row_ptr,
            We + (size_t)l * 256, be + l * 128, Wbeta + (size_t)l * 384,
            xbuf, bnpart);
        k_bnred<<<256, 256, 0, stream>>>(bnpart, bn_acc3 + l * 256);
    }

    // ---- readout (BN affine+ELU of layer-2 fused in) ----
    k_pool<<<313, 256, 0, stream>>>(xbuf, bn_acc3 + 2 * 256,
                                    bn_gamma + 2 * 128, bn_beta + 2 * 128,
                                    Wout, batch, gsum, gcnt);
    k_final<<<1, 64, 0, stream>>>(gsum, gcnt, bout, obias, out);
}

// Round 6
// 622.342 us; speedup vs baseline: 3.6439x; 1.1505x over previous
//
#include <hip/hip_runtime.h>
#include <hip/hip_fp16.h>
#include <math.h>

#define NN 50000
#define EE 800000
#define HIDDEN 128
#define NGRAPH 50
#define GEMM_TILES ((NN + 63) / 64)
#define NB_ATTN 12500

typedef _Float16 half8 __attribute__((ext_vector_type(8)));
typedef float f32x4 __attribute__((ext_vector_type(4)));

// ---------------- CSR degree count + weight transpose (union grid) ----------------
__global__ void k_degprep(const int* __restrict__ eidx, int* __restrict__ cnt,
                          const float* __restrict__ Wq, const float* __restrict__ Wk,
                          const float* __restrict__ Wv, const float* __restrict__ Ws,
                          _Float16* __restrict__ wt) {
    int b = blockIdx.x;
    int t = threadIdx.x;
    if (b < 3125) {
        int e = b * 256 + t;
        if (e < EE) atomicAdd(&cnt[eidx[EE + e]], 1);
    } else {
        int idx = (b - 3125) * 256 + t;   // 12 * 16384 fp16 transposed weights
        if (idx < 12 * 16384) {
            int mat = idx >> 14;
            int l = mat >> 2, w = mat & 3;
            int nk = idx & 16383;
            int n = nk >> 7, k = nk & 127;
            const float* W = (w == 0 ? Wq : w == 1 ? Wk : w == 2 ? Wv : Ws) + (size_t)l * 16384;
            wt[idx] = (_Float16)W[k * 128 + n];
        }
    }
}

// scan + housekeeping: exclusive-scan deg->row_ptr (4 elems/thread), zero cnt,
// zero bn_acc3 / gsum / gcnt
__global__ void k_scan(int* __restrict__ cnt, int* __restrict__ row_ptr,
                       float* __restrict__ bn_acc3, float* __restrict__ gsum,
                       int* __restrict__ gcnt) {
    __shared__ int wsum[16];
    __shared__ int carry_s;
    int t = threadIdx.x;
    int lane = t & 63, w = t >> 6;
    if (t < 768) bn_acc3[t] = 0.f;
    if (t < 64) { gsum[t] = 0.f; gcnt[t] = 0; }
    if (t == 0) carry_s = 0;
    __syncthreads();
    for (int base = 0; base < NN; base += 4096) {
        int i0 = base + t * 4;
        int v[4];
#pragma unroll
        for (int j = 0; j < 4; j++) v[j] = (i0 + j < NN) ? cnt[i0 + j] : 0;
        int s4 = v[0] + v[1] + v[2] + v[3];
        int s = s4;
#pragma unroll
        for (int o = 1; o < 64; o <<= 1) {
            int u = __shfl_up(s, o);
            if (lane >= o) s += u;
        }
        if (lane == 63) wsum[w] = s;
        __syncthreads();
        if (w == 0) {
            int ws = (lane < 16) ? wsum[lane] : 0;
#pragma unroll
            for (int o = 1; o < 16; o <<= 1) {
                int u = __shfl_up(ws, o);
                if (lane >= o) ws += u;
            }
            if (lane < 16) wsum[lane] = ws;
        }
        __syncthreads();
        int wpre = (w == 0) ? 0 : wsum[w - 1];
        int run = carry_s + wpre + s - s4;
#pragma unroll
        for (int j = 0; j < 4; j++) {
            if (i0 + j < NN) { row_ptr[i0 + j] = run; cnt[i0 + j] = 0; run += v[j]; }
        }
        __syncthreads();
        if (t == 0) carry_s += wsum[15];
        __syncthreads();
    }
    if (t == 0) row_ptr[NN] = carry_s;
}

// ---- GEMM tile body via f16 MFMA: q,xr fp32 out; k,v packed OCP fp8 e4m3 ----
__device__ __forceinline__ void gemm_tile(
    const float* __restrict__ X, const _Float16* __restrict__ wt,
    const float* __restrict__ bq, const float* __restrict__ bk,
    const float* __restrict__ bv, const float* __restrict__ bs,
    const float* ab_s, int use_ab, _Float16 (*xs)[136],
    float* __restrict__ qo, unsigned int* __restrict__ kvb, float* __restrict__ xro,
    int m0)
{
    int t = threadIdx.x;
    int lane = t & 63, wid = t >> 6;
#pragma unroll
    for (int i = 0; i < 8; ++i) {
        int f = t + 256 * i;          // float4 index within 64x32
        int r = f >> 5, c4 = (f & 31) << 2;
        float4 val = make_float4(0.f, 0.f, 0.f, 0.f);
        if (m0 + r < NN) val = *(const float4*)&X[(size_t)(m0 + r) * 128 + c4];
        if (use_ab) {
            float4 a = *(const float4*)&ab_s[c4];
            float4 bb = *(const float4*)&ab_s[128 + c4];
            float z;
            z = fmaf(val.x, a.x, bb.x); val.x = z > 0.f ? z : expm1f(z);
            z = fmaf(val.y, a.y, bb.y); val.y = z > 0.f ? z : expm1f(z);
            z = fmaf(val.z, a.z, bb.z); val.z = z > 0.f ? z : expm1f(z);
            z = fmaf(val.w, a.w, bb.w); val.w = z > 0.f ? z : expm1f(z);
        }
        _Float16* dst = &xs[r][c4];
        dst[0] = (_Float16)val.x; dst[1] = (_Float16)val.y;
        dst[2] = (_Float16)val.z; dst[3] = (_Float16)val.w;
    }
    __syncthreads();
    int quad = lane >> 4, l15 = lane & 15;
    int mrow = wid * 16;
    half8 afrag[4];
#pragma unroll
    for (int kk = 0; kk < 4; kk++)
        afrag[kk] = *(const half8*)&xs[mrow + l15][kk * 32 + quad * 8];

#pragma unroll
    for (int nt = 0; nt < 8; nt++) {
        int c = nt * 16 + l15;
        f32x4 acc[4];
#pragma unroll
        for (int w = 0; w < 4; w++) acc[w] = (f32x4){0.f, 0.f, 0.f, 0.f};
#pragma unroll
        for (int kk = 0; kk < 4; kk++) {
            half8 bf[4];
#pragma unroll
            for (int w = 0; w < 4; w++)
                bf[w] = *(const half8*)&wt[(size_t)w * 16384 + c * 128 + kk * 32 + quad * 8];
#pragma unroll
            for (int w = 0; w < 4; w++)
                acc[w] = __builtin_amdgcn_mfma_f32_16x16x32_f16(afrag[kk], bf[w], acc[w], 0, 0, 0);
        }
        float bqv = bq[c], bkv = bk[c], bvv = bv[c], bsv = bs[c];
        int nodebase = m0 + mrow + quad * 4;
#pragma unroll
        for (int r = 0; r < 4; r++) {
            int node = nodebase + r;
            bool ok = node < NN;
            float qv = acc[0][r] + bqv;
            float xv = acc[3][r] + bsv;
            float kf = acc[1][r] + bkv;
            float vf = acc[2][r] + bvv;
            float kf1 = __shfl_xor(kf, 1);
            float vf1 = __shfl_xor(vf, 1);
            if (ok) {
                qo[(size_t)node * 128 + c] = qv;
                xro[(size_t)node * 128 + c] = xv;
                if (!(lane & 1)) {
                    int w2 = __builtin_amdgcn_cvt_pk_fp8_f32(kf, kf1, 0, false);
                    w2 = __builtin_amdgcn_cvt_pk_fp8_f32(vf, vf1, w2, true);
                    kvb[(size_t)node * 64 + (c >> 1)] = (unsigned int)w2;
                }
            }
        }
    }
}

// ---- layer-0 GEMM fused with CSR scatter (independent work, union grid) ----
// v7: scatter writes ONE 16B record {eax, eay, src_bits, 0} instead of 4B esrc
// + 8B eat2 (two lines) — halves partial-line write-allocate traffic (R5: 152MB
// WRITE_SIZE, ~78MB of it scatter inflation).
__global__ __launch_bounds__(256) void k_gemm0scat(
    const float* __restrict__ X, const _Float16* __restrict__ wt,
    const float* __restrict__ bq, const float* __restrict__ bk,
    const float* __restrict__ bv, const float* __restrict__ bs,
    float* __restrict__ qo, unsigned int* __restrict__ kvb, float* __restrict__ xro,
    const int* __restrict__ eidx, const float* __restrict__ eattr,
    const int* __restrict__ row_ptr, int* __restrict__ cur,
    float4* __restrict__ erec)
{
    __shared__ _Float16 xs[64][136];
    int b = blockIdx.x;
    if (b < GEMM_TILES) {
        gemm_tile(X, wt, bq, bk, bv, bs, nullptr, 0, xs, qo, kvb, xro, b * 64);
    } else {
        int e = (b - GEMM_TILES) * 256 + threadIdx.x;
        if (e < EE) {
            int d = eidx[EE + e];
            int s = eidx[e];
            int p = atomicAdd(&cur[d], 1);
            int pos = row_ptr[d] + p;
            float2 ea = *(const float2*)&eattr[2 * (size_t)e];
            erec[pos] = make_float4(ea.x, ea.y, __int_as_float(s), 0.f);
        }
    }
}

// ---- layers 1,2 GEMM (BN affine+ELU on input from bn_acc stats) ----
__global__ __launch_bounds__(256) void k_gemm4(
    const float* __restrict__ X, const _Float16* __restrict__ wt,
    const float* __restrict__ bq, const float* __restrict__ bk,
    const float* __restrict__ bv, const float* __restrict__ bs,
    const float* __restrict__ bn_acc, const float* __restrict__ gamma,
    const float* __restrict__ beta,
    float* __restrict__ qo, unsigned int* __restrict__ kvb, float* __restrict__ xro)
{
    __shared__ _Float16 xs[64][136];
    __shared__ float ab_s[256];
    int t = threadIdx.x;
    if (t < 128) {
        float mu = bn_acc[t] * (1.f / NN);
        float var = bn_acc[128 + t] * (1.f / NN) - mu * mu;
        float inv = rsqrtf(var + 1e-5f);
        float a = inv * gamma[t];
        ab_s[t] = a;
        ab_s[128 + t] = beta[t] - mu * a;
    }
    __syncthreads();
    gemm_tile(X, wt, bq, bk, bv, bs, ab_s, 1, xs, qo, kvb, xro, blockIdx.x * 64);
}

// 16-lane (per-head) sum via DPP row rotations — VALU-only, no DS-pipe ops.
__device__ __forceinline__ float row_sum16(float p) {
    p += __int_as_float(__builtin_amdgcn_update_dpp(0, __float_as_int(p), 0x128, 0xF, 0xF, true)); // row_ror:8
    p += __int_as_float(__builtin_amdgcn_update_dpp(0, __float_as_int(p), 0x124, 0xF, 0xF, true)); // row_ror:4
    p += __int_as_float(__builtin_amdgcn_update_dpp(0, __float_as_int(p), 0x122, 0xF, 0xF, true)); // row_ror:2
    p += __int_as_float(__builtin_amdgcn_update_dpp(0, __float_as_int(p), 0x121, 0xF, 0xF, true)); // row_ror:1
    return p;
}

// ---------------- attention + gate + BN-stats (one wave per dst node) ----------------
// v7: one node per wave (12500 blocks; safe now that the BN tail has no
// contended atomics — R4's 4x-block disaster was the atomics, not the TLP).
// Edge records staged once per 64-edge chunk into LDS (coalesced float4), then
// per-edge wave-uniform ds_read (free broadcast) replaces 3 shfl broadcasts;
// head-reduce via DPP row_sum16 replaces 4 shfl_xor. v6's 8-deep gather
// batching and exact math otherwise retained.
__global__ __launch_bounds__(256) void k_attn(
    const float* __restrict__ q, const unsigned int* __restrict__ kvb,
    const float* __restrict__ xr,
    const float4* __restrict__ erec,
    const int* __restrict__ row_ptr,
    const float* __restrict__ We, const float* __restrict__ be,
    const float* __restrict__ Wb,
    float* __restrict__ out2, float* __restrict__ bnp)
{
    __shared__ float4 es[4][64];
    int t = threadIdx.x;
    int lane = t & 63;
    int wid = t >> 6;
    int n = blockIdx.x * 4 + wid;          // one node per wave, exact cover
    int ch = lane * 2;
    float2 we0 = *(const float2*)&We[ch];
    float2 we1 = *(const float2*)&We[128 + ch];
    float2 beL = *(const float2*)&be[ch];
    float2 wb_o = *(const float2*)&Wb[ch];
    float2 wb_r = *(const float2*)&Wb[128 + ch];
    float2 wb_d = *(const float2*)&Wb[256 + ch];
    const float scale = 0.17677669529663687f;   // 1/sqrt(32)

    int rs = __builtin_amdgcn_readfirstlane(row_ptr[n]);
    int re = __builtin_amdgcn_readfirstlane(row_ptr[n + 1]);
    float2 qv = *(const float2*)&q[(size_t)n * 128 + ch];
    float den = 0.f, ax = 0.f, ay = 0.f;

    auto edge = [&](float eax, float eay, unsigned int w8) {
        auto kf = __builtin_amdgcn_cvt_pk_f32_fp8((int)w8, false);
        auto vf = __builtin_amdgcn_cvt_pk_f32_fp8((int)w8, true);
        float ex_ = fmaf(eax, we0.x, fmaf(eay, we1.x, beL.x));
        float ey_ = fmaf(eax, we0.y, fmaf(eay, we1.y, beL.y));
        float p = qv.x * (kf[0] + ex_) + qv.y * (kf[1] + ey_);
        p = row_sum16(p);
        float exv = __expf(p * scale);
        den += exv;
        ax = fmaf(exv, vf[0] + ex_, ax);
        ay = fmaf(exv, vf[1] + ey_, ay);
    };

    for (int cb = rs; cb < re; cb += 64) {
        int cnum = re - cb; if (cnum > 64) cnum = 64;
        int mi = cb + lane;
        if (mi < re) es[wid][lane] = erec[mi];   // coalesced 16B; same-wave LDS is in-order
        int base = 0;
        for (; base + 8 <= cnum; base += 8) {
            unsigned int kk[8];
#pragma unroll
            for (int j = 0; j < 8; j++) {
                int s = __float_as_int(es[wid][base + j].z);   // uniform ds_read: broadcast
                kk[j] = kvb[(size_t)(unsigned)s * 64 + lane];
            }
#pragma unroll
            for (int j = 0; j < 8; j++) {
                float4 rec = es[wid][base + j];                // uniform ds_read_b128
                edge(rec.x, rec.y, kk[j]);
            }
        }
        for (; base < cnum; ++base) {
            float4 rec = es[wid][base];
            unsigned int k0 = kvb[(size_t)(unsigned)__float_as_int(rec.z) * 64 + lane];
            edge(rec.x, rec.y, k0);
        }
    }

    float rden = 1.f / (den + 1e-16f);
    ax *= rden; ay *= rden;
    // beta gate
    float2 xv = *(const float2*)&xr[(size_t)n * 128 + ch];
    float gp = ax * wb_o.x + ay * wb_o.y + xv.x * wb_r.x + xv.y * wb_r.y
             + (ax - xv.x) * wb_d.x + (ay - xv.y) * wb_d.y;
    gp = row_sum16(gp);
    gp += __shfl_xor(gp, 16);
    gp += __shfl_xor(gp, 32);
    float gate = 1.f / (1.f + __expf(-gp));
    float ox = gate * xv.x + (1.f - gate) * ax;
    float oy = gate * xv.y + (1.f - gate) * ay;
    *(float2*)&out2[(size_t)n * 128 + ch] = make_float2(ox, oy);

    // block-level BN partial reduce -> coalesced per-block record [block][256]
    __shared__ float s_sum[2][256], s_sq[2][256];
    s_sum[0][t] = ox; s_sum[1][t] = oy;
    s_sq[0][t] = ox * ox;  s_sq[1][t] = oy * oy;
    __syncthreads();
    if (t < 64) {
        float sx = s_sum[0][t] + s_sum[0][64 + t] + s_sum[0][128 + t] + s_sum[0][192 + t];
        float sy = s_sum[1][t] + s_sum[1][64 + t] + s_sum[1][128 + t] + s_sum[1][192 + t];
        float qx = s_sq[0][t] + s_sq[0][64 + t] + s_sq[0][128 + t] + s_sq[0][192 + t];
        float qy = s_sq[1][t] + s_sq[1][64 + t] + s_sq[1][128 + t] + s_sq[1][192 + t];
        float2* bp = (float2*)&bnp[(size_t)blockIdx.x * 256];
        bp[t] = make_float2(sx, sy);          // channels 2t, 2t+1
        bp[64 + t] = make_float2(qx, qy);     // channels 128+2t, 129+2t
    }
}

// ---- reduce per-block BN partials [12500][256] -> bn_acc (coalesced, low-contention) ----
__global__ __launch_bounds__(256) void k_bnred(const float* __restrict__ part,
                                               float* __restrict__ bn_acc) {
    int t = threadIdx.x;
    int g = blockIdx.x;                       // 250 blocks x 50 records
    float s = 0.f;
    for (int r = g * 50; r < g * 50 + 50; ++r)
        s += part[(size_t)r * 256 + t];
    atomicAdd(&bn_acc[t], s);                 // 64k atomics over 256 addrs: ~2us
}

// ------- readout: BN affine+ELU+dot(Wout); 313 blocks x 10 chunks to keep
//         gsum/gcnt atomic contention low; LDS per-graph accumulate, one flush -------
__global__ __launch_bounds__(256) void k_pool(const float* __restrict__ x,
                                              const float* __restrict__ bn_acc,
                                              const float* __restrict__ gamma,
                                              const float* __restrict__ beta,
                                              const float* __restrict__ Wout,
                                              const int* __restrict__ batch,
                                              float* __restrict__ gsum, int* __restrict__ gcnt) {
    __shared__ float lsum[NGRAPH];
    __shared__ int lcnt[NGRAPH];
    __shared__ float ab_s[256];
    int t = threadIdx.x;
    if (t < NGRAPH) { lsum[t] = 0.f; lcnt[t] = 0; }
    if (t < 128) {
        float mu = bn_acc[t] * (1.f / NN);
        float var = bn_acc[128 + t] * (1.f / NN) - mu * mu;
        float inv = rsqrtf(var + 1e-5f);
        float a = inv * gamma[t];
        ab_s[t] = a;
        ab_s[128 + t] = beta[t] - mu * a;
    }
    __syncthreads();
    int lane = t & 63;
    int wid = t >> 6;
    int ch = lane * 2;
    float2 wo = *(const float2*)&Wout[ch];
    float2 a = *(const float2*)&ab_s[ch];
    float2 b = *(const float2*)&ab_s[128 + ch];
    for (int chunk = 0; chunk < 10; ++chunk) {
        int base = blockIdx.x * 160 + chunk * 16 + wid * 4;
        float2 xv[4];
#pragma unroll
        for (int i = 0; i < 4; i++) {          // issue all 4 loads before any use
            int n = base + i;
            xv[i] = (n < NN) ? *(const float2*)&x[(size_t)n * 128 + ch]
                             : make_float2(0.f, 0.f);
        }
#pragma unroll
        for (int i = 0; i < 4; i++) {
            int n = base + i;
            if (n < NN) {
                float z0 = fmaf(xv[i].x, a.x, b.x); z0 = z0 > 0.f ? z0 : expm1f(z0);
                float z1 = fmaf(xv[i].y, a.y, b.y); z1 = z1 > 0.f ? z1 : expm1f(z1);
                float p = z0 * wo.x + z1 * wo.y;
                p += __shfl_xor(p, 1);
                p += __shfl_xor(p, 2);
                p += __shfl_xor(p, 4);
                p += __shfl_xor(p, 8);
                p += __shfl_xor(p, 16);
                p += __shfl_xor(p, 32);
                if (lane == 0) {
                    int g = batch[n];
                    atomicAdd(&lsum[g], p);
                    atomicAdd(&lcnt[g], 1);
                }
            }
        }
    }
    __syncthreads();
    if (t < NGRAPH && lcnt[t] > 0) {
        atomicAdd(&gsum[t], lsum[t]);
        atomicAdd(&gcnt[t], lcnt[t]);
    }
}

__global__ void k_final(const float* __restrict__ gsum, const int* __restrict__ gcnt,
                        const float* __restrict__ bout, const float* __restrict__ obias,
                        float* __restrict__ out) {
    int g = threadIdx.x;
    if (g < NGRAPH) out[g] = gsum[g] / fmaxf((float)gcnt[g], 1.f) + bout[0] + obias[0];
}

extern "C" void kernel_launch(void* const* d_in, const int* in_sizes, int n_in,
                              void* d_out, int out_size, void* d_ws, size_t ws_size,
                              hipStream_t stream) {
    const float* x_in       = (const float*)d_in[0];
    const int* eidx         = (const int*)d_in[1];
    const float* eattr      = (const float*)d_in[2];
    const int* batch        = (const int*)d_in[3];
    const float* Wq         = (const float*)d_in[4];
    const float* bq         = (const float*)d_in[5];
    const float* Wk         = (const float*)d_in[6];
    const float* bk         = (const float*)d_in[7];
    const float* Wv         = (const float*)d_in[8];
    const float* bv         = (const float*)d_in[9];
    const float* We         = (const float*)d_in[10];
    const float* be         = (const float*)d_in[11];
    const float* Wskip      = (const float*)d_in[12];
    const float* bskip      = (const float*)d_in[13];
    const float* Wbeta      = (const float*)d_in[14];
    const float* bn_gamma   = (const float*)d_in[15];
    const float* bn_beta    = (const float*)d_in[16];
    const float* Wout       = (const float*)d_in[17];
    const float* bout       = (const float*)d_in[18];
    const float* obias      = (const float*)d_in[19];
    float* out = (float*)d_out;

    char* ws = (char*)d_ws;
    size_t off = 0;
    auto alloc = [&](size_t bytes) -> void* {
        off = (off + 255) & ~(size_t)255;
        void* p = ws + off;
        off += bytes;
        return p;
    };
    const size_t NF = (size_t)NN * 128 * sizeof(float);
    float* xbuf    = (float*)alloc(NF);
    float* qb      = (float*)alloc(NF);
    float* xrb     = (float*)alloc(NF);
    unsigned int* kvb = (unsigned int*)alloc((size_t)NN * 64 * sizeof(unsigned int));
    _Float16* wt   = (_Float16*)alloc((size_t)12 * 16384 * sizeof(_Float16));
    int* row_ptr   = (int*)alloc((NN + 1) * sizeof(int));
    int* cnt       = (int*)alloc(NN * sizeof(int));
    float4* erec   = (float4*)alloc((size_t)EE * sizeof(float4));
    float* bn_acc3 = (float*)alloc(3 * 256 * sizeof(float));
    float* bnpart  = (float*)alloc((size_t)NB_ATTN * 256 * sizeof(float));
    float* gsum    = (float*)alloc(64 * sizeof(float));
    int* gcnt      = (int*)alloc(64 * sizeof(int));
    (void)ws_size; (void)n_in; (void)in_sizes; (void)out_size;

    // ---- CSR degree + weight prep, scan (also zeroes aux) ----
    hipMemsetAsync(cnt, 0, NN * sizeof(int), stream);
    k_degprep<<<3125 + 768, 256, 0, stream>>>(eidx, cnt, Wq, Wk, Wv, Wskip, wt);
    k_scan<<<1, 1024, 0, stream>>>(cnt, row_ptr, bn_acc3, gsum, gcnt);

    // ---- layer 0 GEMM + CSR scatter fused (independent work) ----
    k_gemm0scat<<<GEMM_TILES + 3125, 256, 0, stream>>>(
        x_in, wt, bq, bk, bv, bskip, qb, kvb, xrb,
        eidx, eattr, row_ptr, cnt, erec);
    k_attn<<<NB_ATTN, 256, 0, stream>>>(
        qb, kvb, xrb, erec, row_ptr,
        We, be, Wbeta, xbuf, bnpart);
    k_bnred<<<250, 256, 0, stream>>>(bnpart, bn_acc3);

    // ---- layers 1,2 ----
    for (int l = 1; l < 3; ++l) {
        k_gemm4<<<GEMM_TILES, 256, 0, stream>>>(
            xbuf, wt + (size_t)l * 65536,
            bq + l * 128, bk + l * 128, bv + l * 128, bskip + l * 128,
            bn_acc3 + (l - 1) * 256, bn_gamma + (l - 1) * 128, bn_beta + (l - 1) * 128,
            qb, kvb, xrb);
        k_attn<<<NB_ATTN, 256, 0, stream>>>(
            qb, kvb, xrb, erec, row_ptr,
            We + (size_t)l * 256, be + l * 128, Wbeta + (size_t)l * 384,
            xbuf, bnpart);
        k_bnred<<<250, 256, 0, stream>>>(bnpart, bn_acc3 + l * 256);
    }

    // ---- readout (BN affine+ELU of layer-2 fused in) ----
    k_pool<<<313, 256, 0, stream>>>(xbuf, bn_acc3 + 2 * 256,
                                    bn_gamma + 2 * 128, bn_beta + 2 * 128,
                                    Wout, batch, gsum, gcnt);
    k_final<<<1, 64, 0, stream>>>(gsum, gcnt, bout, obias, out);
}

// Round 7
// 609.852 us; speedup vs baseline: 3.7185x; 1.0205x over previous
//
#include <hip/hip_runtime.h>
#include <hip/hip_fp16.h>
#include <math.h>

#define NN 50000
#define EE 800000
#define HIDDEN 128
#define NGRAPH 50
#define GEMM_TILES ((NN + 63) / 64)
#define NB_ATTN 12500

typedef _Float16 half8 __attribute__((ext_vector_type(8)));
typedef float f32x4 __attribute__((ext_vector_type(4)));

// ---------------- CSR degree count (+rank capture) + weight transpose ----------------
// v8: atomicAdd's return value IS the edge's within-node rank — store it so the
// scatter pass needs no atomic (R6: atomic RMW was the scatter's latency wall).
__global__ void k_degprep(const int* __restrict__ eidx, int* __restrict__ cnt,
                          int* __restrict__ rank,
                          const float* __restrict__ Wq, const float* __restrict__ Wk,
                          const float* __restrict__ Wv, const float* __restrict__ Ws,
                          _Float16* __restrict__ wt) {
    int b = blockIdx.x;
    int t = threadIdx.x;
    if (b < 3125) {
        int e = b * 256 + t;
        if (e < EE) {
            int p = atomicAdd(&cnt[eidx[EE + e]], 1);
            rank[e] = p;
        }
    } else {
        int idx = (b - 3125) * 256 + t;   // 12 * 16384 fp16 transposed weights
        if (idx < 12 * 16384) {
            int mat = idx >> 14;
            int l = mat >> 2, w = mat & 3;
            int nk = idx & 16383;
            int n = nk >> 7, k = nk & 127;
            const float* W = (w == 0 ? Wq : w == 1 ? Wk : w == 2 ? Wv : Ws) + (size_t)l * 16384;
            wt[idx] = (_Float16)W[k * 128 + n];
        }
    }
}

// scan + housekeeping: exclusive-scan deg->row_ptr (4 elems/thread), zero cnt,
// zero bn_acc3 / gsum / gcnt
__global__ void k_scan(int* __restrict__ cnt, int* __restrict__ row_ptr,
                       float* __restrict__ bn_acc3, float* __restrict__ gsum,
                       int* __restrict__ gcnt) {
    __shared__ int wsum[16];
    __shared__ int carry_s;
    int t = threadIdx.x;
    int lane = t & 63, w = t >> 6;
    if (t < 768) bn_acc3[t] = 0.f;
    if (t < 64) { gsum[t] = 0.f; gcnt[t] = 0; }
    if (t == 0) carry_s = 0;
    __syncthreads();
    for (int base = 0; base < NN; base += 4096) {
        int i0 = base + t * 4;
        int v[4];
#pragma unroll
        for (int j = 0; j < 4; j++) v[j] = (i0 + j < NN) ? cnt[i0 + j] : 0;
        int s4 = v[0] + v[1] + v[2] + v[3];
        int s = s4;
#pragma unroll
        for (int o = 1; o < 64; o <<= 1) {
            int u = __shfl_up(s, o);
            if (lane >= o) s += u;
        }
        if (lane == 63) wsum[w] = s;
        __syncthreads();
        if (w == 0) {
            int ws = (lane < 16) ? wsum[lane] : 0;
#pragma unroll
            for (int o = 1; o < 16; o <<= 1) {
                int u = __shfl_up(ws, o);
                if (lane >= o) ws += u;
            }
            if (lane < 16) wsum[lane] = ws;
        }
        __syncthreads();
        int wpre = (w == 0) ? 0 : wsum[w - 1];
        int run = carry_s + wpre + s - s4;
#pragma unroll
        for (int j = 0; j < 4; j++) {
            if (i0 + j < NN) { row_ptr[i0 + j] = run; cnt[i0 + j] = 0; run += v[j]; }
        }
        __syncthreads();
        if (t == 0) carry_s += wsum[15];
        __syncthreads();
    }
    if (t == 0) row_ptr[NN] = carry_s;
}

// ---- GEMM tile body via f16 MFMA: q,xr fp32 out; k,v packed OCP fp8 e4m3 ----
__device__ __forceinline__ void gemm_tile(
    const float* __restrict__ X, const _Float16* __restrict__ wt,
    const float* __restrict__ bq, const float* __restrict__ bk,
    const float* __restrict__ bv, const float* __restrict__ bs,
    const float* ab_s, int use_ab, _Float16 (*xs)[136],
    float* __restrict__ qo, unsigned int* __restrict__ kvb, float* __restrict__ xro,
    int m0)
{
    int t = threadIdx.x;
    int lane = t & 63, wid = t >> 6;
#pragma unroll
    for (int i = 0; i < 8; ++i) {
        int f = t + 256 * i;          // float4 index within 64x32
        int r = f >> 5, c4 = (f & 31) << 2;
        float4 val = make_float4(0.f, 0.f, 0.f, 0.f);
        if (m0 + r < NN) val = *(const float4*)&X[(size_t)(m0 + r) * 128 + c4];
        if (use_ab) {
            float4 a = *(const float4*)&ab_s[c4];
            float4 bb = *(const float4*)&ab_s[128 + c4];
            float z;
            z = fmaf(val.x, a.x, bb.x); val.x = z > 0.f ? z : expm1f(z);
            z = fmaf(val.y, a.y, bb.y); val.y = z > 0.f ? z : expm1f(z);
            z = fmaf(val.z, a.z, bb.z); val.z = z > 0.f ? z : expm1f(z);
            z = fmaf(val.w, a.w, bb.w); val.w = z > 0.f ? z : expm1f(z);
        }
        _Float16* dst = &xs[r][c4];
        dst[0] = (_Float16)val.x; dst[1] = (_Float16)val.y;
        dst[2] = (_Float16)val.z; dst[3] = (_Float16)val.w;
    }
    __syncthreads();
    int quad = lane >> 4, l15 = lane & 15;
    int mrow = wid * 16;
    half8 afrag[4];
#pragma unroll
    for (int kk = 0; kk < 4; kk++)
        afrag[kk] = *(const half8*)&xs[mrow + l15][kk * 32 + quad * 8];

#pragma unroll
    for (int nt = 0; nt < 8; nt++) {
        int c = nt * 16 + l15;
        f32x4 acc[4];
#pragma unroll
        for (int w = 0; w < 4; w++) acc[w] = (f32x4){0.f, 0.f, 0.f, 0.f};
#pragma unroll
        for (int kk = 0; kk < 4; kk++) {
            half8 bf[4];
#pragma unroll
            for (int w = 0; w < 4; w++)
                bf[w] = *(const half8*)&wt[(size_t)w * 16384 + c * 128 + kk * 32 + quad * 8];
#pragma unroll
            for (int w = 0; w < 4; w++)
                acc[w] = __builtin_amdgcn_mfma_f32_16x16x32_f16(afrag[kk], bf[w], acc[w], 0, 0, 0);
        }
        float bqv = bq[c], bkv = bk[c], bvv = bv[c], bsv = bs[c];
        int nodebase = m0 + mrow + quad * 4;
#pragma unroll
        for (int r = 0; r < 4; r++) {
            int node = nodebase + r;
            bool ok = node < NN;
            float qv = acc[0][r] + bqv;
            float xv = acc[3][r] + bsv;
            float kf = acc[1][r] + bkv;
            float vf = acc[2][r] + bvv;
            float kf1 = __shfl_xor(kf, 1);
            float vf1 = __shfl_xor(vf, 1);
            if (ok) {
                qo[(size_t)node * 128 + c] = qv;
                xro[(size_t)node * 128 + c] = xv;
                if (!(lane & 1)) {
                    int w2 = __builtin_amdgcn_cvt_pk_fp8_f32(kf, kf1, 0, false);
                    w2 = __builtin_amdgcn_cvt_pk_fp8_f32(vf, vf1, w2, true);
                    kvb[(size_t)node * 64 + (c >> 1)] = (unsigned int)w2;
                }
            }
        }
    }
}

// ---- layer-0 GEMM fused with CSR scatter (independent work, union grid) ----
// v8: scatter is atomic-free — pos = row_ptr[d] + rank[e] (rank captured in
// k_degprep). Chain is now load->load->store, no RMW round trip.
__global__ __launch_bounds__(256) void k_gemm0scat(
    const float* __restrict__ X, const _Float16* __restrict__ wt,
    const float* __restrict__ bq, const float* __restrict__ bk,
    const float* __restrict__ bv, const float* __restrict__ bs,
    float* __restrict__ qo, unsigned int* __restrict__ kvb, float* __restrict__ xro,
    const int* __restrict__ eidx, const float* __restrict__ eattr,
    const int* __restrict__ row_ptr, const int* __restrict__ rank,
    float4* __restrict__ erec)
{
    __shared__ _Float16 xs[64][136];
    int b = blockIdx.x;
    if (b < GEMM_TILES) {
        gemm_tile(X, wt, bq, bk, bv, bs, nullptr, 0, xs, qo, kvb, xro, b * 64);
    } else {
        int e = (b - GEMM_TILES) * 256 + threadIdx.x;
        if (e < EE) {
            int d = eidx[EE + e];
            int s = eidx[e];
            int rk = rank[e];
            float2 ea = *(const float2*)&eattr[2 * (size_t)e];
            int pos = row_ptr[d] + rk;
            erec[pos] = make_float4(ea.x, ea.y, __int_as_float(s), 0.f);
        }
    }
}

// ---- layers 1,2 GEMM (BN affine+ELU on input from bn_acc stats) ----
__global__ __launch_bounds__(256) void k_gemm4(
    const float* __restrict__ X, const _Float16* __restrict__ wt,
    const float* __restrict__ bq, const float* __restrict__ bk,
    const float* __restrict__ bv, const float* __restrict__ bs,
    const float* __restrict__ bn_acc, const float* __restrict__ gamma,
    const float* __restrict__ beta,
    float* __restrict__ qo, unsigned int* __restrict__ kvb, float* __restrict__ xro)
{
    __shared__ _Float16 xs[64][136];
    __shared__ float ab_s[256];
    int t = threadIdx.x;
    if (t < 128) {
        float mu = bn_acc[t] * (1.f / NN);
        float var = bn_acc[128 + t] * (1.f / NN) - mu * mu;
        float inv = rsqrtf(var + 1e-5f);
        float a = inv * gamma[t];
        ab_s[t] = a;
        ab_s[128 + t] = beta[t] - mu * a;
    }
    __syncthreads();
    gemm_tile(X, wt, bq, bk, bv, bs, ab_s, 1, xs, qo, kvb, xro, blockIdx.x * 64);
}

// 16-lane (per-head) sum via DPP row rotations — VALU-only, no DS-pipe ops.
__device__ __forceinline__ float row_sum16(float p) {
    p += __int_as_float(__builtin_amdgcn_update_dpp(0, __float_as_int(p), 0x128, 0xF, 0xF, true)); // row_ror:8
    p += __int_as_float(__builtin_amdgcn_update_dpp(0, __float_as_int(p), 0x124, 0xF, 0xF, true)); // row_ror:4
    p += __int_as_float(__builtin_amdgcn_update_dpp(0, __float_as_int(p), 0x122, 0xF, 0xF, true)); // row_ror:2
    p += __int_as_float(__builtin_amdgcn_update_dpp(0, __float_as_int(p), 0x121, 0xF, 0xF, true)); // row_ror:1
    return p;
}

// ---------------- attention + gate + BN-stats (one wave per dst node) ----------------
// v8: cross-group DOUBLE-BUFFERED gathers (kkA/kkB + sched_barrier fences):
// group g+1's 8 kvb gathers issue before group g's compute, hiding the latency
// wall under ~480cy of VALU. Groups padded to 8 via clamp+mask — no serial
// scalar tail. Otherwise v7 structure (LDS-staged records, DPP reduce,
// coalesced BN partials).
__global__ __launch_bounds__(256) void k_attn(
    const float* __restrict__ q, const unsigned int* __restrict__ kvb,
    const float* __restrict__ xr,
    const float4* __restrict__ erec,
    const int* __restrict__ row_ptr,
    const float* __restrict__ We, const float* __restrict__ be,
    const float* __restrict__ Wb,
    float* __restrict__ out2, float* __restrict__ bnp)
{
    __shared__ float4 es[4][64];
    int t = threadIdx.x;
    int lane = t & 63;
    int wid = t >> 6;
    int n = blockIdx.x * 4 + wid;          // one node per wave, exact cover
    int ch = lane * 2;
    float2 we0 = *(const float2*)&We[ch];
    float2 we1 = *(const float2*)&We[128 + ch];
    float2 beL = *(const float2*)&be[ch];
    const float scale = 0.17677669529663687f;   // 1/sqrt(32)

    int rs = __builtin_amdgcn_readfirstlane(row_ptr[n]);
    int re = __builtin_amdgcn_readfirstlane(row_ptr[n + 1]);
    float2 qv = *(const float2*)&q[(size_t)n * 128 + ch];
    float2 xv = *(const float2*)&xr[(size_t)n * 128 + ch];   // prefetch early
    float den = 0.f, ax = 0.f, ay = 0.f;

    for (int cb = rs; cb < re; cb += 64) {
        int cnum = re - cb; if (cnum > 64) cnum = 64;
        int mi = cb + lane;
        if (mi < re) es[wid][lane] = erec[mi];   // coalesced 16B; same-wave LDS in order
        int cm1 = cnum - 1;
        int ng = (cnum + 7) >> 3;                // padded groups of 8 (clamp+mask)
        unsigned int kkA[8], kkB[8];

#define LOAD8(KK, B0) do {                                                   \
        _Pragma("unroll")                                                    \
        for (int j = 0; j < 8; j++) {                                        \
            int o = (B0) + j; int oc = o < cm1 ? o : cm1;                    \
            int s = __float_as_int(es[wid][oc].z);                           \
            KK[j] = kvb[(size_t)(unsigned)s * 64 + lane];                    \
        }                                                                    \
    } while (0)

#define COMP8(KK, B0) do {                                                   \
        _Pragma("unroll")                                                    \
        for (int j = 0; j < 8; j++) {                                        \
            int o = (B0) + j; int oc = o < cm1 ? o : cm1;                    \
            float4 rec = es[wid][oc];                                        \
            auto kf = __builtin_amdgcn_cvt_pk_f32_fp8((int)KK[j], false);    \
            auto vf = __builtin_amdgcn_cvt_pk_f32_fp8((int)KK[j], true);     \
            float ex_ = fmaf(rec.x, we0.x, fmaf(rec.y, we1.x, beL.x));       \
            float ey_ = fmaf(rec.x, we0.y, fmaf(rec.y, we1.y, beL.y));       \
            float p = qv.x * (kf[0] + ex_) + qv.y * (kf[1] + ey_);           \
            p = row_sum16(p);                                                \
            float exv = (o < cnum) ? __expf(p * scale) : 0.f;                \
            den += exv;                                                      \
            ax = fmaf(exv, vf[0] + ex_, ax);                                 \
            ay = fmaf(exv, vf[1] + ey_, ay);                                 \
        }                                                                    \
    } while (0)

        LOAD8(kkA, 0);
        __builtin_amdgcn_sched_barrier(0);
        int g = 0;
        for (;;) {
            if (g + 1 < ng) { LOAD8(kkB, (g + 1) * 8); __builtin_amdgcn_sched_barrier(0); }
            COMP8(kkA, g * 8);
            ++g; if (g >= ng) break;
            if (g + 1 < ng) { LOAD8(kkA, (g + 1) * 8); __builtin_amdgcn_sched_barrier(0); }
            COMP8(kkB, g * 8);
            ++g; if (g >= ng) break;
        }
#undef LOAD8
#undef COMP8
    }

    float rden = 1.f / (den + 1e-16f);
    ax *= rden; ay *= rden;
    // beta gate
    float2 wb_o = *(const float2*)&Wb[ch];
    float2 wb_r = *(const float2*)&Wb[128 + ch];
    float2 wb_d = *(const float2*)&Wb[256 + ch];
    float gp = ax * wb_o.x + ay * wb_o.y + xv.x * wb_r.x + xv.y * wb_r.y
             + (ax - xv.x) * wb_d.x + (ay - xv.y) * wb_d.y;
    gp = row_sum16(gp);
    gp += __shfl_xor(gp, 16);
    gp += __shfl_xor(gp, 32);
    float gate = 1.f / (1.f + __expf(-gp));
    float ox = gate * xv.x + (1.f - gate) * ax;
    float oy = gate * xv.y + (1.f - gate) * ay;
    *(float2*)&out2[(size_t)n * 128 + ch] = make_float2(ox, oy);

    // block-level BN partial reduce -> coalesced per-block record [block][256]
    __shared__ float s_sum[2][256], s_sq[2][256];
    s_sum[0][t] = ox; s_sum[1][t] = oy;
    s_sq[0][t] = ox * ox;  s_sq[1][t] = oy * oy;
    __syncthreads();
    if (t < 64) {
        float sx = s_sum[0][t] + s_sum[0][64 + t] + s_sum[0][128 + t] + s_sum[0][192 + t];
        float sy = s_sum[1][t] + s_sum[1][64 + t] + s_sum[1][128 + t] + s_sum[1][192 + t];
        float qx = s_sq[0][t] + s_sq[0][64 + t] + s_sq[0][128 + t] + s_sq[0][192 + t];
        float qy = s_sq[1][t] + s_sq[1][64 + t] + s_sq[1][128 + t] + s_sq[1][192 + t];
        float2* bp = (float2*)&bnp[(size_t)blockIdx.x * 256];
        bp[t] = make_float2(sx, sy);          // channels 2t, 2t+1
        bp[64 + t] = make_float2(qx, qy);     // channels 128+2t, 129+2t
    }
}

// ---- reduce per-block BN partials [12500][256] -> bn_acc (coalesced, low-contention) ----
__global__ __launch_bounds__(256) void k_bnred(const float* __restrict__ part,
                                               float* __restrict__ bn_acc) {
    int t = threadIdx.x;
    int g = blockIdx.x;                       // 250 blocks x 50 records
    float s = 0.f;
    for (int r = g * 50; r < g * 50 + 50; ++r)
        s += part[(size_t)r * 256 + t];
    atomicAdd(&bn_acc[t], s);                 // 64k atomics over 256 addrs: ~2us
}

// ------- readout: BN affine+ELU+dot(Wout); 313 blocks x 10 chunks to keep
//         gsum/gcnt atomic contention low; LDS per-graph accumulate, one flush -------
__global__ __launch_bounds__(256) void k_pool(const float* __restrict__ x,
                                              const float* __restrict__ bn_acc,
                                              const float* __restrict__ gamma,
                                              const float* __restrict__ beta,
                                              const float* __restrict__ Wout,
                                              const int* __restrict__ batch,
                                              float* __restrict__ gsum, int* __restrict__ gcnt) {
    __shared__ float lsum[NGRAPH];
    __shared__ int lcnt[NGRAPH];
    __shared__ float ab_s[256];
    int t = threadIdx.x;
    if (t < NGRAPH) { lsum[t] = 0.f; lcnt[t] = 0; }
    if (t < 128) {
        float mu = bn_acc[t] * (1.f / NN);
        float var = bn_acc[128 + t] * (1.f / NN) - mu * mu;
        float inv = rsqrtf(var + 1e-5f);
        float a = inv * gamma[t];
        ab_s[t] = a;
        ab_s[128 + t] = beta[t] - mu * a;
    }
    __syncthreads();
    int lane = t & 63;
    int wid = t >> 6;
    int ch = lane * 2;
    float2 wo = *(const float2*)&Wout[ch];
    float2 a = *(const float2*)&ab_s[ch];
    float2 b = *(const float2*)&ab_s[128 + ch];
    for (int chunk = 0; chunk < 10; ++chunk) {
        int base = blockIdx.x * 160 + chunk * 16 + wid * 4;
        float2 xv[4];
#pragma unroll
        for (int i = 0; i < 4; i++) {          // issue all 4 loads before any use
            int n = base + i;
            xv[i] = (n < NN) ? *(const float2*)&x[(size_t)n * 128 + ch]
                             : make_float2(0.f, 0.f);
        }
#pragma unroll
        for (int i = 0; i < 4; i++) {
            int n = base + i;
            if (n < NN) {
                float z0 = fmaf(xv[i].x, a.x, b.x); z0 = z0 > 0.f ? z0 : expm1f(z0);
                float z1 = fmaf(xv[i].y, a.y, b.y); z1 = z1 > 0.f ? z1 : expm1f(z1);
                float p = z0 * wo.x + z1 * wo.y;
                p += __shfl_xor(p, 1);
                p += __shfl_xor(p, 2);
                p += __shfl_xor(p, 4);
                p += __shfl_xor(p, 8);
                p += __shfl_xor(p, 16);
                p += __shfl_xor(p, 32);
                if (lane == 0) {
                    int g = batch[n];
                    atomicAdd(&lsum[g], p);
                    atomicAdd(&lcnt[g], 1);
                }
            }
        }
    }
    __syncthreads();
    if (t < NGRAPH && lcnt[t] > 0) {
        atomicAdd(&gsum[t], lsum[t]);
        atomicAdd(&gcnt[t], lcnt[t]);
    }
}

__global__ void k_final(const float* __restrict__ gsum, const int* __restrict__ gcnt,
                        const float* __restrict__ bout, const float* __restrict__ obias,
                        float* __restrict__ out) {
    int g = threadIdx.x;
    if (g < NGRAPH) out[g] = gsum[g] / fmaxf((float)gcnt[g], 1.f) + bout[0] + obias[0];
}

extern "C" void kernel_launch(void* const* d_in, const int* in_sizes, int n_in,
                              void* d_out, int out_size, void* d_ws, size_t ws_size,
                              hipStream_t stream) {
    const float* x_in       = (const float*)d_in[0];
    const int* eidx         = (const int*)d_in[1];
    const float* eattr      = (const float*)d_in[2];
    const int* batch        = (const int*)d_in[3];
    const float* Wq         = (const float*)d_in[4];
    const float* bq         = (const float*)d_in[5];
    const float* Wk         = (const float*)d_in[6];
    const float* bk         = (const float*)d_in[7];
    const float* Wv         = (const float*)d_in[8];
    const float* bv         = (const float*)d_in[9];
    const float* We         = (const float*)d_in[10];
    const float* be         = (const float*)d_in[11];
    const float* Wskip      = (const float*)d_in[12];
    const float* bskip      = (const float*)d_in[13];
    const float* Wbeta      = (const float*)d_in[14];
    const float* bn_gamma   = (const float*)d_in[15];
    const float* bn_beta    = (const float*)d_in[16];
    const float* Wout       = (const float*)d_in[17];
    const float* bout       = (const float*)d_in[18];
    const float* obias      = (const float*)d_in[19];
    float* out = (float*)d_out;

    char* ws = (char*)d_ws;
    size_t off = 0;
    auto alloc = [&](size_t bytes) -> void* {
        off = (off + 255) & ~(size_t)255;
        void* p = ws + off;
        off += bytes;
        return p;
    };
    const size_t NF = (size_t)NN * 128 * sizeof(float);
    float* xbuf    = (float*)alloc(NF);
    float* qb      = (float*)alloc(NF);
    float* xrb     = (float*)alloc(NF);
    unsigned int* kvb = (unsigned int*)alloc((size_t)NN * 64 * sizeof(unsigned int));
    _Float16* wt   = (_Float16*)alloc((size_t)12 * 16384 * sizeof(_Float16));
    int* row_ptr   = (int*)alloc((NN + 1) * sizeof(int));
    int* cnt       = (int*)alloc(NN * sizeof(int));
    int* rank      = (int*)alloc(EE * sizeof(int));
    float4* erec   = (float4*)alloc((size_t)EE * sizeof(float4));
    float* bn_acc3 = (float*)alloc(3 * 256 * sizeof(float));
    float* bnpart  = (float*)alloc((size_t)NB_ATTN * 256 * sizeof(float));
    float* gsum    = (float*)alloc(64 * sizeof(float));
    int* gcnt      = (int*)alloc(64 * sizeof(int));
    (void)ws_size; (void)n_in; (void)in_sizes; (void)out_size;

    // ---- CSR degree + rank + weight prep, scan (also zeroes aux) ----
    hipMemsetAsync(cnt, 0, NN * sizeof(int), stream);
    k_degprep<<<3125 + 768, 256, 0, stream>>>(eidx, cnt, rank, Wq, Wk, Wv, Wskip, wt);
    k_scan<<<1, 1024, 0, stream>>>(cnt, row_ptr, bn_acc3, gsum, gcnt);

    // ---- layer 0 GEMM + CSR scatter fused (independent work) ----
    k_gemm0scat<<<GEMM_TILES + 3125, 256, 0, stream>>>(
        x_in, wt, bq, bk, bv, bskip, qb, kvb, xrb,
        eidx, eattr, row_ptr, rank, erec);
    k_attn<<<NB_ATTN, 256, 0, stream>>>(
        qb, kvb, xrb, erec, row_ptr,
        We, be, Wbeta, xbuf, bnpart);
    k_bnred<<<250, 256, 0, stream>>>(bnpart, bn_acc3);

    // ---- layers 1,2 ----
    for (int l = 1; l < 3; ++l) {
        k_gemm4<<<GEMM_TILES, 256, 0, stream>>>(
            xbuf, wt + (size_t)l * 65536,
            bq + l * 128, bk + l * 128, bv + l * 128, bskip + l * 128,
            bn_acc3 + (l - 1) * 256, bn_gamma + (l - 1) * 128, bn_beta + (l - 1) * 128,
            qb, kvb, xrb);
        k_attn<<<NB_ATTN, 256, 0, stream>>>(
            qb, kvb, xrb, erec, row_ptr,
            We + (size_t)l * 256, be + l * 128, Wbeta + (size_t)l * 384,
            xbuf, bnpart);
        k_bnred<<<250, 256, 0, stream>>>(bnpart, bn_acc3 + l * 256);
    }

    // ---- readout (BN affine+ELU of layer-2 fused in) ----
    k_pool<<<313, 256, 0, stream>>>(xbuf, bn_acc3 + 2 * 256,
                                    bn_gamma + 2 * 128, bn_beta + 2 * 128,
                                    Wout, batch, gsum, gcnt);
    k_final<<<1, 64, 0, stream>>>(gsum, gcnt, bout, obias, out);
}